// Round 14
// baseline (1070.403 us; speedup 1.0000x reference)
//
#include <hip/hip_runtime.h>

#define D 128
#define GG 128
#define SLOTS 64

typedef __attribute__((ext_vector_type(8))) short bf16x8;
typedef __attribute__((ext_vector_type(4))) float f32x4;

__device__ __forceinline__ short f2bf(float f) {
  unsigned u = __float_as_uint(f);
  unsigned r = u + 0x7fffu + ((u >> 16) & 1u);
  return (short)(r >> 16);
}
__device__ __forceinline__ float bf2f(unsigned short h) {
  return __uint_as_float(((unsigned)h) << 16);
}

__device__ __forceinline__ void bn_coef(float s, float q, float invn, float g, float b,
                                        float& sc, float& sh) {
  float mu = s * invn;
  float var = q * invn - mu * mu;
  sc = g * rsqrtf(var + 1e-5f);
  sh = b - mu * sc;
}

// ---------------- CSR build (padded to multiple of 4 per row) ----------------
__global__ void k_deg(int E, const int* __restrict__ dst, int* __restrict__ deg) {
  int e = blockIdx.x * 256 + threadIdx.x;
  if (e < E) atomicAdd(&deg[dst[e]], 1);
}

__global__ void k_scan1(int N, const int* __restrict__ deg,
                        int* __restrict__ incl, int* __restrict__ blksum) {
  __shared__ int s[256];
  int t = threadIdx.x, n = blockIdx.x * 256 + t;
  int v = (n < N) ? ((deg[n] + 3) & ~3) : 0;
  s[t] = v; __syncthreads();
  for (int off = 1; off < 256; off <<= 1) {
    int x = (t >= off) ? s[t - off] : 0;
    __syncthreads();
    s[t] += x;
    __syncthreads();
  }
  if (n < N) incl[n] = s[t];
  if (t == 255) blksum[blockIdx.x] = s[255];
}

__global__ void k_scan2(int B, int* __restrict__ blksum) {
  __shared__ int s[512];
  int t = threadIdx.x;
  s[t] = (t < B) ? blksum[t] : 0;
  __syncthreads();
  for (int off = 1; off < 512; off <<= 1) {
    int x = (t >= off) ? s[t - off] : 0;
    __syncthreads();
    s[t] += x;
    __syncthreads();
  }
  if (t < B) blksum[t] = s[t];
}

__global__ void k_scan3(int N, const int* __restrict__ incl, const int* __restrict__ blksum,
                        const int* __restrict__ deg, int* __restrict__ row_ptr) {
  int n = blockIdx.x * 256 + threadIdx.x;
  if (n >= N) return;
  int b = n >> 8;
  int off = (b > 0) ? blksum[b - 1] : 0;
  int pdeg = (deg[n] + 3) & ~3;
  row_ptr[n] = off + incl[n] - pdeg;
  if (n == N - 1) row_ptr[N] = off + incl[n];
}

__global__ void k_fill(int E, const int* __restrict__ src, const int* __restrict__ dst,
                       const float* __restrict__ ea, const int* __restrict__ row_ptr,
                       int* __restrict__ cursor, int4* __restrict__ er) {
  int e = blockIdx.x * 256 + threadIdx.x;
  if (e >= E) return;
  int d = dst[e];
  int pos = row_ptr[d] + atomicAdd(&cursor[d], 1);
  er[pos] = make_int4(src[e] << 8, __float_as_int(ea[2 * e]), __float_as_int(ea[2 * e + 1]), 0);
}

__global__ void k_padfill(int N, const int* __restrict__ deg, const int* __restrict__ row_ptr,
                          int4* __restrict__ er) {
  int n = blockIdx.x * 256 + threadIdx.x;
  if (n >= N) return;
  int s = row_ptr[n] + deg[n], e = row_ptr[n + 1];
  int4 pad = make_int4(N << 8, 0, 0, 0);
  for (int p = s; p < e; ++p) er[p] = pad;
}

__global__ void k_sentinel(int N, short* __restrict__ h2) {
  h2[(size_t)N * D + threadIdx.x] = f2bf(-1e30f);
}

// pack weights: W1T[l][n=256][k=128], W2T[l][n=128][k=256]  (bf16, n-major)
__global__ void k_pack(const float* __restrict__ gW1, const float* __restrict__ gW2,
                       short* __restrict__ w1t, short* __restrict__ w2t) {
  int id = blockIdx.x * 256 + threadIdx.x;
  if (id < 5 * 256 * 128) {
    int l = id / 32768, r = id % 32768, n = r / 128, k = r % 128;
    w1t[id] = f2bf(gW1[l * 32768 + k * 256 + n]);
  }
  if (id < 5 * 128 * 256) {
    int l = id / 32768, r = id % 32768, n = r / 256, k = r % 256;
    w2t[id] = f2bf(gW2[l * 32768 + k * 128 + n]);
  }
}

// reduce SLOTS partials; optionally emit BN coefs and/or raw sums
__global__ void k_coef(int NC, float invn,
                       const float* __restrict__ part_s, const float* __restrict__ part_q,
                       const float* __restrict__ g, const float* __restrict__ b,
                       float* __restrict__ sc, float* __restrict__ sh,
                       float* __restrict__ outs, float* __restrict__ outq) {
  int t = threadIdx.x;
  if (t >= NC) return;
  float s = 0.f, q = 0.f;
  #pragma unroll 4
  for (int i = 0; i < SLOTS; ++i) {
    s += part_s[i * NC + t];
    q += part_q[i * NC + t];
  }
  if (outs) { outs[t] = s; outq[t] = q; }
  if (g) {
    float a, c;
    bn_coef(s, q, invn, g[t], b[t], a, c);
    sc[t] = a; sh[t] = c;
  }
}

// Fused: h = (encoder | bn2+relu(z2)) + vn[batch]; h2(bf16); pooled per-graph sums.
__global__ void k_nodeprep(int N, int mode,
    const int* __restrict__ x, const int* __restrict__ depth,
    const float* __restrict__ te, const float* __restrict__ ae, const float* __restrict__ de,
    const short* __restrict__ z2, const float* __restrict__ s2, const float* __restrict__ q2,
    const float* __restrict__ g2, const float* __restrict__ b2,
    int vn_mode, const float* __restrict__ vne,
    const float* __restrict__ t2v, const float* __restrict__ vs2, const float* __restrict__ vq2,
    const float* __restrict__ vg2, const float* __restrict__ vb2,
    const int* __restrict__ batch,
    short* __restrict__ h2, float* __restrict__ vt_pool, int do_pool)
{
  int t = threadIdx.x;
  int d0 = (t & 63) * 2;
  int grp = t >> 6;
  int n0 = blockIdx.x * 32 + grp * 8;
  float invn = 1.0f / (float)N;
  float sc0 = 0.f, sh0 = 0.f, sc1 = 0.f, sh1 = 0.f;
  float vsc0 = 0.f, vsh0 = 0.f, vsc1 = 0.f, vsh1 = 0.f;
  if (mode == 1) {
    bn_coef(s2[d0], q2[d0], invn, g2[d0], b2[d0], sc0, sh0);
    bn_coef(s2[d0 + 1], q2[d0 + 1], invn, g2[d0 + 1], b2[d0 + 1], sc1, sh1);
  }
  if (vn_mode == 1) {
    bn_coef(vs2[d0], vq2[d0], 1.0f / (float)GG, vg2[d0], vb2[d0], vsc0, vsh0);
    bn_coef(vs2[d0 + 1], vq2[d0 + 1], 1.0f / (float)GG, vg2[d0 + 1], vb2[d0 + 1], vsc1, vsh1);
  }
  int cur = -1; float a0 = 0.f, a1 = 0.f;
  for (int k = 0; k < 8; ++k) {
    int n = n0 + k;
    if (n >= N) break;
    float h0, h1;
    if (mode == 0) {
      int x0 = x[2 * n], x1 = x[2 * n + 1], dp = depth[n];
      float2 e0 = *(const float2*)(te + (size_t)x0 * D + d0);
      float2 e1 = *(const float2*)(ae + (size_t)x1 * D + d0);
      float2 e2 = *(const float2*)(de + (size_t)dp * D + d0);
      h0 = e0.x + e1.x + e2.x;
      h1 = e0.y + e1.y + e2.y;
    } else {
      unsigned zv = *(const unsigned*)(z2 + (size_t)n * D + d0);
      h0 = fmaxf(bf2f((unsigned short)(zv & 0xffff)) * sc0 + sh0, 0.f);
      h1 = fmaxf(bf2f((unsigned short)(zv >> 16))    * sc1 + sh1, 0.f);
    }
    int g = batch[n];
    float v0, v1;
    if (vn_mode == 0) { v0 = vne[d0]; v1 = vne[d0 + 1]; }
    else {
      float2 tv = *(const float2*)(t2v + (size_t)g * D + d0);
      v0 = fmaxf(tv.x * vsc0 + vsh0, 0.f);
      v1 = fmaxf(tv.y * vsc1 + vsh1, 0.f);
    }
    h0 += v0; h1 += v1;
    unsigned o = ((unsigned)(unsigned short)f2bf(h0)) |
                 (((unsigned)(unsigned short)f2bf(h1)) << 16);
    *(unsigned*)(h2 + (size_t)n * D + d0) = o;
    if (do_pool) {
      if (g != cur) {
        if (cur >= 0) {
          atomicAdd(&vt_pool[cur * D + d0], a0);
          atomicAdd(&vt_pool[cur * D + d0 + 1], a1);
        }
        cur = g; a0 = 0.f; a1 = 0.f;
      }
      a0 += h0; a1 += h1;
    }
  }
  if (do_pool && cur >= 0) {
    atomicAdd(&vt_pool[cur * D + d0], a0);
    atomicAdd(&vt_pool[cur * D + d0 + 1], a1);
  }
}

// Gather aggregation over padded CSR (unchanged, proven).
__global__ void __launch_bounds__(256) k_gather(int N,
    const int* __restrict__ row_ptr, const int4* __restrict__ er,
    const float* __restrict__ ew, const float* __restrict__ eb,
    const float* __restrict__ epsp,
    const short* __restrict__ h2, short* __restrict__ am)
{
  int t = threadIdx.x;
  int w = t >> 6, l = t & 63;
  int n = blockIdx.x * 4 + w;
  if (n >= N) return;
  const char* h2b = (const char*)h2;
  int lb = l << 2;
  int d0 = l * 2;
  float ew00 = ew[d0], ew01 = ew[d0 + 1];
  float ew10 = ew[D + d0], ew11 = ew[D + d0 + 1];
  float eb0 = eb[d0], eb1 = eb[d0 + 1];
  float ep1 = 1.0f + epsp[0];
  unsigned hv = *(const unsigned*)(h2b + ((size_t)n << 8) + lb);
  float acc0 = ep1 * bf2f((unsigned short)(hv & 0xffff));
  float acc1 = ep1 * bf2f((unsigned short)(hv >> 16));
  int beg = row_ptr[n], end = row_ptr[n + 1];
  for (int i = beg; i < end; i += 4) {
    int4 e0 = er[i], e1 = er[i + 1], e2 = er[i + 2], e3 = er[i + 3];
    unsigned v0 = *(const unsigned*)(h2b + e0.x + lb);
    unsigned v1 = *(const unsigned*)(h2b + e1.x + lb);
    unsigned v2 = *(const unsigned*)(h2b + e2.x + lb);
    unsigned v3 = *(const unsigned*)(h2b + e3.x + lb);
    float a0x = __int_as_float(e0.y), a0y = __int_as_float(e0.z);
    float a1x = __int_as_float(e1.y), a1y = __int_as_float(e1.z);
    float a2x = __int_as_float(e2.y), a2y = __int_as_float(e2.z);
    float a3x = __int_as_float(e3.y), a3y = __int_as_float(e3.z);
    acc0 += fmaxf(bf2f((unsigned short)(v0 & 0xffff)) + a0x * ew00 + a0y * ew10 + eb0, 0.f);
    acc1 += fmaxf(bf2f((unsigned short)(v0 >> 16))    + a0x * ew01 + a0y * ew11 + eb1, 0.f);
    acc0 += fmaxf(bf2f((unsigned short)(v1 & 0xffff)) + a1x * ew00 + a1y * ew10 + eb0, 0.f);
    acc1 += fmaxf(bf2f((unsigned short)(v1 >> 16))    + a1x * ew01 + a1y * ew11 + eb1, 0.f);
    acc0 += fmaxf(bf2f((unsigned short)(v2 & 0xffff)) + a2x * ew00 + a2y * ew10 + eb0, 0.f);
    acc1 += fmaxf(bf2f((unsigned short)(v2 >> 16))    + a2x * ew01 + a2y * ew11 + eb1, 0.f);
    acc0 += fmaxf(bf2f((unsigned short)(v3 & 0xffff)) + a3x * ew00 + a3y * ew10 + eb0, 0.f);
    acc1 += fmaxf(bf2f((unsigned short)(v3 >> 16))    + a3x * ew01 + a3y * ew11 + eb1, 0.f);
  }
  unsigned o = ((unsigned)(unsigned short)f2bf(acc0)) |
               (((unsigned)(unsigned short)f2bf(acc1)) << 16);
  *(unsigned*)(am + (size_t)n * D + d0) = o;
}

// k_stats: column sum/sumsq of t1 = am@W1 + b1 WITHOUT storing t1.
// 64-row tile, cols in 2 chunks of 128 (acc[2][4] per wave). B direct from L2.
__global__ void __launch_bounds__(256) k_stats(int N,
    const short* __restrict__ A, const short* __restrict__ Bt,
    const float* __restrict__ bias,
    float* __restrict__ part_s, float* __restrict__ part_q)
{
  __shared__ __align__(16) char As[16384];   // 64 x 256B
  __shared__ float cs[256], cq[256];
  int t = threadIdx.x;
  int m0 = blockIdx.x * 64;
  int w = t >> 6, l = t & 63;
  int wr = w >> 1, wc = w & 1;
  int lm = l & 15, kb = l >> 4;
  cs[t] = 0.f; cq[t] = 0.f;

  #pragma unroll
  for (int r = 0; r < 4; ++r) {
    int p = (r * 256 + t) * 16;
    int row = p >> 8, c = p & 255;
    int gr = m0 + row; if (gr > N - 1) gr = N - 1;
    bf16x8 v = *(const bf16x8*)((const char*)A + (size_t)gr * 256 + c);
    *(bf16x8*)(As + row * 256 + (c ^ ((row & 7) << 4))) = v;
  }
  __syncthreads();

  #pragma unroll
  for (int ch = 0; ch < 2; ++ch) {
    f32x4 acc[2][4];
    #pragma unroll
    for (int j = 0; j < 4; ++j) {
      float bj = bias[ch * 128 + wc * 64 + j * 16 + lm];
      acc[0][j] = (f32x4){bj, bj, bj, bj};
      acc[1][j] = (f32x4){bj, bj, bj, bj};
    }
    #pragma unroll
    for (int ks = 0; ks < 4; ++ks) {
      int kB = ks * 64 + kb * 16;
      bf16x8 fa[2], fb[4];
      #pragma unroll
      for (int j = 0; j < 4; ++j) {
        int cl = ch * 128 + wc * 64 + j * 16 + lm;
        fb[j] = *(const bf16x8*)((const char*)Bt + (size_t)cl * 256 + kB);
      }
      #pragma unroll
      for (int i = 0; i < 2; ++i) {
        int rl = wr * 32 + i * 16 + lm;
        fa[i] = *(const bf16x8*)(As + rl * 256 + (kB ^ ((rl & 7) << 4)));
      }
      #pragma unroll
      for (int i = 0; i < 2; ++i)
        #pragma unroll
        for (int j = 0; j < 4; ++j)
          acc[i][j] = __builtin_amdgcn_mfma_f32_16x16x32_bf16(fa[i], fb[j], acc[i][j], 0, 0, 0);
    }
    #pragma unroll
    for (int j = 0; j < 4; ++j) {
      int col = ch * 128 + wc * 64 + j * 16 + lm;
      float sv = 0.f, qv = 0.f;
      #pragma unroll
      for (int i = 0; i < 2; ++i) {
        #pragma unroll
        for (int r = 0; r < 4; ++r) {
          int row = m0 + wr * 32 + i * 16 + kb * 4 + r;
          float vv = acc[i][j][r];
          if (row < N) { sv += vv; qv += vv * vv; }
        }
      }
      sv += __shfl_xor(sv, 16); sv += __shfl_xor(sv, 32);
      qv += __shfl_xor(qv, 16); qv += __shfl_xor(qv, 32);
      if (l < 16) { atomicAdd(&cs[col], sv); atomicAdd(&cq[col], qv); }
    }
  }
  __syncthreads();
  {
    int slot = blockIdx.x & (SLOTS - 1);
    atomicAdd(&part_s[(size_t)slot * 256 + t], cs[t]);
    atomicAdd(&part_q[(size_t)slot * 256 + t], cq[t]);
  }
}

// k_mlp: z2 = relu(bn1(am@W1+b1)) @ W2 + b2, t1/a2 never hit HBM.
// Phase1 recomputes t1 chunks (same order as k_stats), bn1+relu -> a2 LDS (64x512B).
// Phase2: z2 = a2 @ W2 + b2 with outer-BN slot partials.
__global__ void __launch_bounds__(256) k_mlp(int N,
    const short* __restrict__ A, const short* __restrict__ W1t, const short* __restrict__ W2t,
    const float* __restrict__ b1, const float* __restrict__ sc1, const float* __restrict__ sh1,
    const float* __restrict__ b2,
    short* __restrict__ z2, float* __restrict__ part_s, float* __restrict__ part_q)
{
  __shared__ __align__(16) char As[16384];   // am tile 64 x 256B
  __shared__ __align__(16) char A2[32768];   // a2 tile 64 x 512B
  __shared__ float cs[128], cq[128];
  int t = threadIdx.x;
  int m0 = blockIdx.x * 64;
  int w = t >> 6, l = t & 63;
  int wr = w >> 1, wc = w & 1;
  int lm = l & 15, kb = l >> 4;
  if (t < 128) { cs[t] = 0.f; cq[t] = 0.f; }

  #pragma unroll
  for (int r = 0; r < 4; ++r) {
    int p = (r * 256 + t) * 16;
    int row = p >> 8, c = p & 255;
    int gr = m0 + row; if (gr > N - 1) gr = N - 1;
    bf16x8 v = *(const bf16x8*)((const char*)A + (size_t)gr * 256 + c);
    *(bf16x8*)(As + row * 256 + (c ^ ((row & 7) << 4))) = v;
  }
  __syncthreads();

  // phase 1: t1 chunks -> bn1+relu -> A2
  #pragma unroll
  for (int ch = 0; ch < 2; ++ch) {
    f32x4 acc[2][4];
    float scj[4], shj[4];
    #pragma unroll
    for (int j = 0; j < 4; ++j) {
      int col = ch * 128 + wc * 64 + j * 16 + lm;
      float bj = b1[col];
      acc[0][j] = (f32x4){bj, bj, bj, bj};
      acc[1][j] = (f32x4){bj, bj, bj, bj};
      scj[j] = sc1[col]; shj[j] = sh1[col];
    }
    #pragma unroll
    for (int ks = 0; ks < 4; ++ks) {
      int kB = ks * 64 + kb * 16;
      bf16x8 fa[2], fb[4];
      #pragma unroll
      for (int j = 0; j < 4; ++j) {
        int cl = ch * 128 + wc * 64 + j * 16 + lm;
        fb[j] = *(const bf16x8*)((const char*)W1t + (size_t)cl * 256 + kB);
      }
      #pragma unroll
      for (int i = 0; i < 2; ++i) {
        int rl = wr * 32 + i * 16 + lm;
        fa[i] = *(const bf16x8*)(As + rl * 256 + (kB ^ ((rl & 7) << 4)));
      }
      #pragma unroll
      for (int i = 0; i < 2; ++i)
        #pragma unroll
        for (int j = 0; j < 4; ++j)
          acc[i][j] = __builtin_amdgcn_mfma_f32_16x16x32_bf16(fa[i], fb[j], acc[i][j], 0, 0, 0);
    }
    #pragma unroll
    for (int j = 0; j < 4; ++j) {
      int colb = (ch * 128 + wc * 64 + j * 16 + lm) * 2;
      #pragma unroll
      for (int i = 0; i < 2; ++i) {
        int rowb = wr * 32 + i * 16 + kb * 4;
        #pragma unroll
        for (int r = 0; r < 4; ++r) {
          int row = rowb + r;
          float vv = fmaxf(acc[i][j][r] * scj[j] + shj[j], 0.f);
          *(short*)(A2 + row * 512 + (colb ^ ((row & 7) << 4))) = f2bf(vv);
        }
      }
    }
  }
  __syncthreads();

  // phase 2: z2 = a2 @ W2 + b2
  f32x4 acc2[2][4];
  #pragma unroll
  for (int j = 0; j < 4; ++j) {
    float bj = b2[wc * 64 + j * 16 + lm];
    acc2[0][j] = (f32x4){bj, bj, bj, bj};
    acc2[1][j] = (f32x4){bj, bj, bj, bj};
  }
  #pragma unroll
  for (int ks = 0; ks < 8; ++ks) {
    int kB = ks * 64 + kb * 16;
    bf16x8 fa[2], fb[4];
    #pragma unroll
    for (int j = 0; j < 4; ++j) {
      int cl = wc * 64 + j * 16 + lm;
      fb[j] = *(const bf16x8*)((const char*)W2t + (size_t)cl * 512 + kB);
    }
    #pragma unroll
    for (int i = 0; i < 2; ++i) {
      int rl = wr * 32 + i * 16 + lm;
      fa[i] = *(const bf16x8*)(A2 + rl * 512 + (kB ^ ((rl & 7) << 4)));
    }
    #pragma unroll
    for (int i = 0; i < 2; ++i)
      #pragma unroll
      for (int j = 0; j < 4; ++j)
        acc2[i][j] = __builtin_amdgcn_mfma_f32_16x16x32_bf16(fa[i], fb[j], acc2[i][j], 0, 0, 0);
  }

  #pragma unroll
  for (int j = 0; j < 4; ++j) {
    int col = wc * 64 + j * 16 + lm;
    float sv = 0.f, qv = 0.f;
    #pragma unroll
    for (int i = 0; i < 2; ++i) {
      #pragma unroll
      for (int r = 0; r < 4; ++r) {
        int row = m0 + wr * 32 + i * 16 + kb * 4 + r;
        float vv = acc2[i][j][r];
        if (row < N) { z2[(size_t)row * 128 + col] = f2bf(vv); sv += vv; qv += vv * vv; }
      }
    }
    sv += __shfl_xor(sv, 16); sv += __shfl_xor(sv, 32);
    qv += __shfl_xor(qv, 16); qv += __shfl_xor(qv, 32);
    if (l < 16) { atomicAdd(&cs[col], sv); atomicAdd(&cq[col], qv); }
  }
  __syncthreads();
  if (t < 128) {
    int slot = blockIdx.x & (SLOTS - 1);
    atomicAdd(&part_s[(size_t)slot * 128 + t], cs[t]);
    atomicAdd(&part_q[(size_t)slot * 128 + t], cq[t]);
  }
}

// vn MLP stage 1 (fp32, tiny)
__global__ void k_vn1(const float* __restrict__ vt_pool,
    int vn_mode, const float* __restrict__ vne, const float* __restrict__ t2v,
    const float* __restrict__ vs2, const float* __restrict__ vq2,
    const float* __restrict__ vg2, const float* __restrict__ vb2,
    const float* __restrict__ W1, const float* __restrict__ b1,
    float* __restrict__ t1v, float* __restrict__ s1, float* __restrict__ q1)
{
  __shared__ float vrow[128];
  int g = blockIdx.x, t = threadIdx.x;
  if (t < 128) {
    float vnv;
    if (vn_mode == 0) vnv = vne[t];
    else {
      float sc, sh;
      bn_coef(vs2[t], vq2[t], 1.f / (float)GG, vg2[t], vb2[t], sc, sh);
      vnv = fmaxf(t2v[g * D + t] * sc + sh, 0.f);
    }
    vrow[t] = vt_pool[g * D + t] + vnv;
  }
  __syncthreads();
  float acc = b1[t];
  for (int k = 0; k < 128; ++k) acc += vrow[k] * W1[k * 256 + t];
  t1v[g * 256 + t] = acc;
  atomicAdd(&s1[t], acc);
  atomicAdd(&q1[t], acc * acc);
}

// vn MLP stage 2 (fp32, tiny)
__global__ void k_vn2(const float* __restrict__ t1v,
    const float* __restrict__ s1, const float* __restrict__ q1,
    const float* __restrict__ g1, const float* __restrict__ b1bn,
    const float* __restrict__ W2, const float* __restrict__ b2,
    float* __restrict__ t2v, float* __restrict__ s2, float* __restrict__ q2)
{
  __shared__ float p[256];
  int g = blockIdx.x, t = threadIdx.x;
  for (int u = t; u < 256; u += 128) {
    float sc, sh;
    bn_coef(s1[u], q1[u], 1.f / (float)GG, g1[u], b1bn[u], sc, sh);
    p[u] = fmaxf(t1v[g * 256 + u] * sc + sh, 0.f);
  }
  __syncthreads();
  float acc = b2[t];
  for (int k = 0; k < 256; ++k) acc += p[k] * W2[k * D + t];
  t2v[g * D + t] = acc;
  atomicAdd(&s2[t], acc);
  atomicAdd(&q2[t], acc * acc);
}

// final: out = bn2(z2)
__global__ void k_out(int N, const short* __restrict__ z2,
    const float* __restrict__ s2, const float* __restrict__ q2,
    const float* __restrict__ g2, const float* __restrict__ b2, float* __restrict__ out)
{
  long long idx = (long long)blockIdx.x * 256 + threadIdx.x;
  long long base = idx * 2;
  if (base >= (long long)N * D) return;
  int d = (int)(base & (D - 1));
  float invn = 1.f / (float)N;
  unsigned v = *(const unsigned*)(z2 + base);
  float sc0, sh0, sc1, sh1;
  bn_coef(s2[d], q2[d], invn, g2[d], b2[d], sc0, sh0);
  bn_coef(s2[d + 1], q2[d + 1], invn, g2[d + 1], b2[d + 1], sc1, sh1);
  out[base]     = bf2f((unsigned short)(v & 0xffff)) * sc0 + sh0;
  out[base + 1] = bf2f((unsigned short)(v >> 16))    * sc1 + sh1;
}

extern "C" void kernel_launch(void* const* d_in, const int* in_sizes, int n_in,
                              void* d_out, int out_size, void* d_ws, size_t ws_size,
                              hipStream_t stream) {
  const int*   x     = (const int*)d_in[0];
  const int*   depth = (const int*)d_in[1];
  const int*   eidx  = (const int*)d_in[2];
  const int*   batch = (const int*)d_in[3];
  const float* ea    = (const float*)d_in[4];
  const float* te    = (const float*)d_in[5];
  const float* aemb  = (const float*)d_in[6];
  const float* de    = (const float*)d_in[7];
  const float* vne   = (const float*)d_in[8];
  const float* epsp  = (const float*)d_in[9];
  const float* eW    = (const float*)d_in[10];
  const float* eb    = (const float*)d_in[11];
  const float* gW1   = (const float*)d_in[12];
  const float* gb1   = (const float*)d_in[13];
  const float* gbng  = (const float*)d_in[14];
  const float* gbnb  = (const float*)d_in[15];
  const float* gW2   = (const float*)d_in[16];
  const float* gb2   = (const float*)d_in[17];
  const float* bng   = (const float*)d_in[18];
  const float* bnb   = (const float*)d_in[19];
  const float* vW1   = (const float*)d_in[20];
  const float* vb1   = (const float*)d_in[21];
  const float* vbn1g = (const float*)d_in[22];
  const float* vbn1b = (const float*)d_in[23];
  const float* vW2   = (const float*)d_in[24];
  const float* vb2   = (const float*)d_in[25];
  const float* vbn2g = (const float*)d_in[26];
  const float* vbn2b = (const float*)d_in[27];

  int N = in_sizes[0] / 2;
  int E = in_sizes[2] / 2;
  const int* src = eidx;
  const int* dst = eidx + E;

  char* wsp = (char*)d_ws;
  auto alloc = [&](size_t bytes) -> char* {
    char* p = wsp; wsp += (bytes + 15) & ~(size_t)15; return p;
  };
  short* h2         = (short*)alloc((size_t)(N + 1) * 128 * 2);
  short* am         = (short*)alloc((size_t)N * 128 * 2);
  short* z2         = (short*)alloc((size_t)N * 128 * 2);
  short* w1t        = (short*)alloc((size_t)5 * 256 * 128 * 2);
  short* w2t        = (short*)alloc((size_t)5 * 128 * 256 * 2);
  int*   row_ptr    = (int*)alloc((size_t)(N + 1) * 4);
  int*   incl       = (int*)alloc((size_t)N * 4);
  int*   blksum     = (int*)alloc(512 * 4);
  int4*  er         = (int4*)alloc(((size_t)E + 3 * (size_t)N + 16) * 16);
  float* sc1        = (float*)alloc(256 * 4);
  float* sh1        = (float*)alloc(256 * 4);
  // zeroed region
  char* zero_base = wsp;
  int*  deg    = (int*)alloc((size_t)N * 4);
  int*  cursor = (int*)alloc((size_t)N * 4);
  float* sp = (float*)wsp;
  float *p1s[5], *p1q[5], *p2s[5], *p2q[5], *s2s[5], *q2s[5];
  for (int l = 0; l < 5; ++l) {
    p1s[l]=sp; sp+=SLOTS*256; p1q[l]=sp; sp+=SLOTS*256;
    p2s[l]=sp; sp+=SLOTS*128; p2q[l]=sp; sp+=SLOTS*128;
    s2s[l]=sp; sp+=128; q2s[l]=sp; sp+=128;
  }
  float *vt[4], *t1v[4], *t2v[4], *vs1[4], *vq1[4], *vs2[4], *vq2[4];
  for (int l = 0; l < 4; ++l) {
    vt[l]=sp;  sp+=GG*D;
    t1v[l]=sp; sp+=GG*256;
    t2v[l]=sp; sp+=GG*D;
    vs1[l]=sp; sp+=256; vq1[l]=sp; sp+=256;
    vs2[l]=sp; sp+=128; vq2[l]=sp; sp+=128;
  }
  size_t zero_bytes = (size_t)((char*)sp - zero_base);
  hipMemsetAsync(zero_base, 0, zero_bytes, stream);

  // CSR build (padded)
  int eblk = (E + 255) / 256;
  int nblk = (N + 255) / 256;
  int B = nblk;
  k_deg<<<eblk, 256, 0, stream>>>(E, dst, deg);
  k_scan1<<<nblk, 256, 0, stream>>>(N, deg, incl, blksum);
  k_scan2<<<1, 512, 0, stream>>>(B, blksum);
  k_scan3<<<nblk, 256, 0, stream>>>(N, incl, blksum, deg, row_ptr);
  k_fill<<<eblk, 256, 0, stream>>>(E, src, dst, ea, row_ptr, cursor, er);
  k_padfill<<<nblk, 256, 0, stream>>>(N, deg, row_ptr, er);
  k_sentinel<<<1, 128, 0, stream>>>(N, h2);

  k_pack<<<(5 * 256 * 128 + 255) / 256, 256, 0, stream>>>(gW1, gW2, w1t, w2t);

  int nblk_a = (N + 31) / 32;
  int nblk_gth = (N + 3) / 4;
  int nblk_m = (N + 63) / 64;
  float invn = 1.f / (float)N;

  for (int l = 0; l < 5; ++l) {
    int mode    = (l == 0) ? 0 : 1;
    int vn_mode = (l == 0) ? 0 : 1;
    int do_pool = (l < 4) ? 1 : 0;
    const float* ps2  = (l > 0) ? s2s[l-1] : s2s[0];
    const float* pq2  = (l > 0) ? q2s[l-1] : q2s[0];
    const float* pg2  = (l > 0) ? bng + (l-1)*D : bng;
    const float* pb2  = (l > 0) ? bnb + (l-1)*D : bnb;
    const float* pt2v = (l > 0) ? t2v[l-1] : t2v[0];
    const float* pvs2 = (l > 0) ? vs2[l-1] : vs2[0];
    const float* pvq2 = (l > 0) ? vq2[l-1] : vq2[0];
    const float* pvg2 = (l > 0) ? vbn2g + (l-1)*D : vbn2g;
    const float* pvb2 = (l > 0) ? vbn2b + (l-1)*D : vbn2b;

    k_nodeprep<<<nblk_a, 256, 0, stream>>>(N, mode, x, depth, te, aemb, de,
        z2, ps2, pq2, pg2, pb2,
        vn_mode, vne, pt2v, pvs2, pvq2, pvg2, pvb2,
        batch, h2, do_pool ? vt[l] : vt[0], do_pool);

    k_gather<<<nblk_gth, 256, 0, stream>>>(N, row_ptr, er,
        eW + l*2*D, eb + l*D, epsp + l, h2, am);

    k_stats<<<nblk_m, 256, 0, stream>>>(N, am, w1t + (size_t)l*256*128,
        gb1 + l*256, p1s[l], p1q[l]);

    k_coef<<<1, 256, 0, stream>>>(256, invn, p1s[l], p1q[l],
        gbng + l*256, gbnb + l*256, sc1, sh1, nullptr, nullptr);

    k_mlp<<<nblk_m, 256, 0, stream>>>(N, am,
        w1t + (size_t)l*256*128, w2t + (size_t)l*128*256,
        gb1 + l*256, sc1, sh1, gb2 + l*128, z2, p2s[l], p2q[l]);

    k_coef<<<1, 128, 0, stream>>>(128, invn, p2s[l], p2q[l],
        nullptr, nullptr, nullptr, nullptr, s2s[l], q2s[l]);

    if (l < 4) {
      k_vn1<<<GG, 256, 0, stream>>>(vt[l], vn_mode, vne, pt2v, pvs2, pvq2, pvg2, pvb2,
          vW1 + (size_t)l*128*256, vb1 + l*256, t1v[l], vs1[l], vq1[l]);
      k_vn2<<<GG, 128, 0, stream>>>(t1v[l], vs1[l], vq1[l],
          vbn1g + l*256, vbn1b + l*256,
          vW2 + (size_t)l*256*128, vb2 + l*128, t2v[l], vs2[l], vq2[l]);
    }
  }

  k_out<<<(int)(((long long)N * D / 2 + 255) / 256), 256, 0, stream>>>(N, z2, s2s[4], q2s[4],
      bng + 4*D, bnb + 4*D, (float*)d_out);
}

// Round 15
// 900.183 us; speedup vs baseline: 1.1891x; 1.1891x over previous
//
#include <hip/hip_runtime.h>

#define D 128
#define GG 128
#define SLOTS 64

typedef __attribute__((ext_vector_type(8))) short bf16x8;
typedef __attribute__((ext_vector_type(4))) float f32x4;

__device__ __forceinline__ short f2bf(float f) {
  unsigned u = __float_as_uint(f);
  unsigned r = u + 0x7fffu + ((u >> 16) & 1u);
  return (short)(r >> 16);
}
__device__ __forceinline__ float bf2f(unsigned short h) {
  return __uint_as_float(((unsigned)h) << 16);
}

__device__ __forceinline__ void bn_coef(float s, float q, float invn, float g, float b,
                                        float& sc, float& sh) {
  float mu = s * invn;
  float var = q * invn - mu * mu;
  sc = g * rsqrtf(var + 1e-5f);
  sh = b - mu * sc;
}

// ---------------- CSR build (padded to multiple of 4 per row) ----------------
__global__ void k_deg(int E, const int* __restrict__ dst, int* __restrict__ deg) {
  int e = blockIdx.x * 256 + threadIdx.x;
  if (e < E) atomicAdd(&deg[dst[e]], 1);
}

__global__ void k_scan1(int N, const int* __restrict__ deg,
                        int* __restrict__ incl, int* __restrict__ blksum) {
  __shared__ int s[256];
  int t = threadIdx.x, n = blockIdx.x * 256 + t;
  int v = (n < N) ? ((deg[n] + 3) & ~3) : 0;
  s[t] = v; __syncthreads();
  for (int off = 1; off < 256; off <<= 1) {
    int x = (t >= off) ? s[t - off] : 0;
    __syncthreads();
    s[t] += x;
    __syncthreads();
  }
  if (n < N) incl[n] = s[t];
  if (t == 255) blksum[blockIdx.x] = s[255];
}

__global__ void k_scan2(int B, int* __restrict__ blksum) {
  __shared__ int s[512];
  int t = threadIdx.x;
  s[t] = (t < B) ? blksum[t] : 0;
  __syncthreads();
  for (int off = 1; off < 512; off <<= 1) {
    int x = (t >= off) ? s[t - off] : 0;
    __syncthreads();
    s[t] += x;
    __syncthreads();
  }
  if (t < B) blksum[t] = s[t];
}

__global__ void k_scan3(int N, const int* __restrict__ incl, const int* __restrict__ blksum,
                        const int* __restrict__ deg, int* __restrict__ row_ptr) {
  int n = blockIdx.x * 256 + threadIdx.x;
  if (n >= N) return;
  int b = n >> 8;
  int off = (b > 0) ? blksum[b - 1] : 0;
  int pdeg = (deg[n] + 3) & ~3;
  row_ptr[n] = off + incl[n] - pdeg;
  if (n == N - 1) row_ptr[N] = off + incl[n];
}

__global__ void k_fill(int E, const int* __restrict__ src, const int* __restrict__ dst,
                       const float* __restrict__ ea, const int* __restrict__ row_ptr,
                       int* __restrict__ cursor, int4* __restrict__ er) {
  int e = blockIdx.x * 256 + threadIdx.x;
  if (e >= E) return;
  int d = dst[e];
  int pos = row_ptr[d] + atomicAdd(&cursor[d], 1);
  er[pos] = make_int4(src[e] << 8, __float_as_int(ea[2 * e]), __float_as_int(ea[2 * e + 1]), 0);
}

__global__ void k_padfill(int N, const int* __restrict__ deg, const int* __restrict__ row_ptr,
                          int4* __restrict__ er) {
  int n = blockIdx.x * 256 + threadIdx.x;
  if (n >= N) return;
  int s = row_ptr[n] + deg[n], e = row_ptr[n + 1];
  int4 pad = make_int4(N << 8, 0, 0, 0);
  for (int p = s; p < e; ++p) er[p] = pad;
}

__global__ void k_sentinel(int N, short* __restrict__ h2) {
  h2[(size_t)N * D + threadIdx.x] = f2bf(-1e30f);
}

// pack weights: W1T[l][n=256][k=128], W2T[l][n=128][k=256]  (bf16, n-major)
__global__ void k_pack(const float* __restrict__ gW1, const float* __restrict__ gW2,
                       short* __restrict__ w1t, short* __restrict__ w2t) {
  int id = blockIdx.x * 256 + threadIdx.x;
  if (id < 5 * 256 * 128) {
    int l = id / 32768, r = id % 32768, n = r / 128, k = r % 128;
    w1t[id] = f2bf(gW1[l * 32768 + k * 256 + n]);
  }
  if (id < 5 * 128 * 256) {
    int l = id / 32768, r = id % 32768, n = r / 256, k = r % 256;
    w2t[id] = f2bf(gW2[l * 32768 + k * 128 + n]);
  }
}

// reduce SLOTS partials -> raw sums
__global__ void k_coef(int NC,
                       const float* __restrict__ part_s, const float* __restrict__ part_q,
                       float* __restrict__ outs, float* __restrict__ outq) {
  int t = threadIdx.x;
  if (t >= NC) return;
  float s = 0.f, q = 0.f;
  #pragma unroll 4
  for (int i = 0; i < SLOTS; ++i) {
    s += part_s[i * NC + t];
    q += part_q[i * NC + t];
  }
  outs[t] = s; outq[t] = q;
}

// Fused: h = (encoder | bn2+relu(z2)) + vn[batch]; h2(bf16); pooled per-graph sums.
__global__ void k_nodeprep(int N, int mode,
    const int* __restrict__ x, const int* __restrict__ depth,
    const float* __restrict__ te, const float* __restrict__ ae, const float* __restrict__ de,
    const short* __restrict__ z2, const float* __restrict__ s2, const float* __restrict__ q2,
    const float* __restrict__ g2, const float* __restrict__ b2,
    int vn_mode, const float* __restrict__ vne,
    const float* __restrict__ t2v, const float* __restrict__ vs2, const float* __restrict__ vq2,
    const float* __restrict__ vg2, const float* __restrict__ vb2,
    const int* __restrict__ batch,
    short* __restrict__ h2, float* __restrict__ vt_pool, int do_pool)
{
  int t = threadIdx.x;
  int d0 = (t & 63) * 2;
  int grp = t >> 6;
  int n0 = blockIdx.x * 32 + grp * 8;
  float invn = 1.0f / (float)N;
  float sc0 = 0.f, sh0 = 0.f, sc1 = 0.f, sh1 = 0.f;
  float vsc0 = 0.f, vsh0 = 0.f, vsc1 = 0.f, vsh1 = 0.f;
  if (mode == 1) {
    bn_coef(s2[d0], q2[d0], invn, g2[d0], b2[d0], sc0, sh0);
    bn_coef(s2[d0 + 1], q2[d0 + 1], invn, g2[d0 + 1], b2[d0 + 1], sc1, sh1);
  }
  if (vn_mode == 1) {
    bn_coef(vs2[d0], vq2[d0], 1.0f / (float)GG, vg2[d0], vb2[d0], vsc0, vsh0);
    bn_coef(vs2[d0 + 1], vq2[d0 + 1], 1.0f / (float)GG, vg2[d0 + 1], vb2[d0 + 1], vsc1, vsh1);
  }
  int cur = -1; float a0 = 0.f, a1 = 0.f;
  for (int k = 0; k < 8; ++k) {
    int n = n0 + k;
    if (n >= N) break;
    float h0, h1;
    if (mode == 0) {
      int x0 = x[2 * n], x1 = x[2 * n + 1], dp = depth[n];
      float2 e0 = *(const float2*)(te + (size_t)x0 * D + d0);
      float2 e1 = *(const float2*)(ae + (size_t)x1 * D + d0);
      float2 e2 = *(const float2*)(de + (size_t)dp * D + d0);
      h0 = e0.x + e1.x + e2.x;
      h1 = e0.y + e1.y + e2.y;
    } else {
      unsigned zv = *(const unsigned*)(z2 + (size_t)n * D + d0);
      h0 = fmaxf(bf2f((unsigned short)(zv & 0xffff)) * sc0 + sh0, 0.f);
      h1 = fmaxf(bf2f((unsigned short)(zv >> 16))    * sc1 + sh1, 0.f);
    }
    int g = batch[n];
    float v0, v1;
    if (vn_mode == 0) { v0 = vne[d0]; v1 = vne[d0 + 1]; }
    else {
      float2 tv = *(const float2*)(t2v + (size_t)g * D + d0);
      v0 = fmaxf(tv.x * vsc0 + vsh0, 0.f);
      v1 = fmaxf(tv.y * vsc1 + vsh1, 0.f);
    }
    h0 += v0; h1 += v1;
    unsigned o = ((unsigned)(unsigned short)f2bf(h0)) |
                 (((unsigned)(unsigned short)f2bf(h1)) << 16);
    *(unsigned*)(h2 + (size_t)n * D + d0) = o;
    if (do_pool) {
      if (g != cur) {
        if (cur >= 0) {
          atomicAdd(&vt_pool[cur * D + d0], a0);
          atomicAdd(&vt_pool[cur * D + d0 + 1], a1);
        }
        cur = g; a0 = 0.f; a1 = 0.f;
      }
      a0 += h0; a1 += h1;
    }
  }
  if (do_pool && cur >= 0) {
    atomicAdd(&vt_pool[cur * D + d0], a0);
    atomicAdd(&vt_pool[cur * D + d0 + 1], a1);
  }
}

// Gather aggregation over padded CSR (unchanged, proven).
__global__ void __launch_bounds__(256) k_gather(int N,
    const int* __restrict__ row_ptr, const int4* __restrict__ er,
    const float* __restrict__ ew, const float* __restrict__ eb,
    const float* __restrict__ epsp,
    const short* __restrict__ h2, short* __restrict__ am)
{
  int t = threadIdx.x;
  int w = t >> 6, l = t & 63;
  int n = blockIdx.x * 4 + w;
  if (n >= N) return;
  const char* h2b = (const char*)h2;
  int lb = l << 2;
  int d0 = l * 2;
  float ew00 = ew[d0], ew01 = ew[d0 + 1];
  float ew10 = ew[D + d0], ew11 = ew[D + d0 + 1];
  float eb0 = eb[d0], eb1 = eb[d0 + 1];
  float ep1 = 1.0f + epsp[0];
  unsigned hv = *(const unsigned*)(h2b + ((size_t)n << 8) + lb);
  float acc0 = ep1 * bf2f((unsigned short)(hv & 0xffff));
  float acc1 = ep1 * bf2f((unsigned short)(hv >> 16));
  int beg = row_ptr[n], end = row_ptr[n + 1];
  for (int i = beg; i < end; i += 4) {
    int4 e0 = er[i], e1 = er[i + 1], e2 = er[i + 2], e3 = er[i + 3];
    unsigned v0 = *(const unsigned*)(h2b + e0.x + lb);
    unsigned v1 = *(const unsigned*)(h2b + e1.x + lb);
    unsigned v2 = *(const unsigned*)(h2b + e2.x + lb);
    unsigned v3 = *(const unsigned*)(h2b + e3.x + lb);
    float a0x = __int_as_float(e0.y), a0y = __int_as_float(e0.z);
    float a1x = __int_as_float(e1.y), a1y = __int_as_float(e1.z);
    float a2x = __int_as_float(e2.y), a2y = __int_as_float(e2.z);
    float a3x = __int_as_float(e3.y), a3y = __int_as_float(e3.z);
    acc0 += fmaxf(bf2f((unsigned short)(v0 & 0xffff)) + a0x * ew00 + a0y * ew10 + eb0, 0.f);
    acc1 += fmaxf(bf2f((unsigned short)(v0 >> 16))    + a0x * ew01 + a0y * ew11 + eb1, 0.f);
    acc0 += fmaxf(bf2f((unsigned short)(v1 & 0xffff)) + a1x * ew00 + a1y * ew10 + eb0, 0.f);
    acc1 += fmaxf(bf2f((unsigned short)(v1 >> 16))    + a1x * ew01 + a1y * ew11 + eb1, 0.f);
    acc0 += fmaxf(bf2f((unsigned short)(v2 & 0xffff)) + a2x * ew00 + a2y * ew10 + eb0, 0.f);
    acc1 += fmaxf(bf2f((unsigned short)(v2 >> 16))    + a2x * ew01 + a2y * ew11 + eb1, 0.f);
    acc0 += fmaxf(bf2f((unsigned short)(v3 & 0xffff)) + a3x * ew00 + a3y * ew10 + eb0, 0.f);
    acc1 += fmaxf(bf2f((unsigned short)(v3 >> 16))    + a3x * ew01 + a3y * ew11 + eb1, 0.f);
  }
  unsigned o = ((unsigned)(unsigned short)f2bf(acc0)) |
               (((unsigned)(unsigned short)f2bf(acc1)) << 16);
  *(unsigned*)(am + (size_t)n * D + d0) = o;
}

// gemm1 full-width: t1[128-row tile x 256 cols] = am @ W1 + b1. A staged ONCE;
// cols in 2 chunks of 128, Bs restaged per chunk, acc[4][4] reused. Stats -> partials.
__global__ void __launch_bounds__(256, 2) k_gemm1w(int N,
    const short* __restrict__ A, const short* __restrict__ Bt,
    const float* __restrict__ bias,
    short* __restrict__ C,
    float* __restrict__ part_s, float* __restrict__ part_q)
{
  __shared__ __align__(16) char As[32768];   // 128 rows x 256 B
  __shared__ __align__(16) char Bs[32768];   // 128 cols x 256 B (per chunk)
  __shared__ float cs[256], cq[256];
  int t = threadIdx.x;
  int m0 = blockIdx.x * 128;
  int w = t >> 6, l = t & 63;
  int wr = w >> 1, wc = w & 1;
  int lm = l & 15, kb = l >> 4;
  cs[t] = 0.f; cq[t] = 0.f;

  // stage A once: 8 rounds x 256 thr x 16B
  #pragma unroll
  for (int r = 0; r < 8; ++r) {
    int p = (r * 256 + t) * 16;
    int row = p >> 8, c = p & 255;
    int gr = m0 + row; if (gr > N - 1) gr = N - 1;
    bf16x8 v = *(const bf16x8*)((const char*)A + (size_t)gr * 256 + c);
    *(bf16x8*)(As + row * 256 + (c ^ ((row & 7) << 4))) = v;
  }

  #pragma unroll
  for (int ch = 0; ch < 2; ++ch) {
    if (ch > 0) __syncthreads();    // prev chunk MFMA done before Bs overwrite
    // stage B chunk: 8 rounds
    #pragma unroll
    for (int r = 0; r < 8; ++r) {
      int p = (r * 256 + t) * 16;
      int col = p >> 8, c = p & 255;
      bf16x8 v = *(const bf16x8*)((const char*)Bt + (size_t)(ch * 128 + col) * 256 + c);
      *(bf16x8*)(Bs + col * 256 + (c ^ ((col & 7) << 4))) = v;
    }
    __syncthreads();

    f32x4 acc[4][4];
    #pragma unroll
    for (int j = 0; j < 4; ++j) {
      float bj = bias[ch * 128 + wc * 64 + j * 16 + lm];
      #pragma unroll
      for (int i = 0; i < 4; ++i) acc[i][j] = (f32x4){bj, bj, bj, bj};
    }
    #pragma unroll
    for (int ks = 0; ks < 4; ++ks) {
      int kB = ks * 64 + kb * 16;
      bf16x8 fa[4], fb[4];
      #pragma unroll
      for (int i = 0; i < 4; ++i) {
        int rl = wr * 64 + i * 16 + lm;
        fa[i] = *(const bf16x8*)(As + rl * 256 + (kB ^ ((rl & 7) << 4)));
      }
      #pragma unroll
      for (int j = 0; j < 4; ++j) {
        int cl = wc * 64 + j * 16 + lm;
        fb[j] = *(const bf16x8*)(Bs + cl * 256 + (kB ^ ((cl & 7) << 4)));
      }
      #pragma unroll
      for (int i = 0; i < 4; ++i)
        #pragma unroll
        for (int j = 0; j < 4; ++j)
          acc[i][j] = __builtin_amdgcn_mfma_f32_16x16x32_bf16(fa[i], fb[j], acc[i][j], 0, 0, 0);
    }
    // epilogue for this chunk: C writes + per-col stats
    #pragma unroll
    for (int j = 0; j < 4; ++j) {
      int col = ch * 128 + wc * 64 + j * 16 + lm;
      float sv = 0.f, qv = 0.f;
      #pragma unroll
      for (int i = 0; i < 4; ++i) {
        #pragma unroll
        for (int r = 0; r < 4; ++r) {
          int row = m0 + wr * 64 + i * 16 + kb * 4 + r;
          float vv = acc[i][j][r];
          if (row < N) { C[(size_t)row * 256 + col] = f2bf(vv); sv += vv; qv += vv * vv; }
        }
      }
      sv += __shfl_xor(sv, 16); sv += __shfl_xor(sv, 32);
      qv += __shfl_xor(qv, 16); qv += __shfl_xor(qv, 32);
      if (l < 16) { atomicAdd(&cs[col], sv); atomicAdd(&cq[col], qv); }
    }
  }
  __syncthreads();
  {
    int slot = blockIdx.x & (SLOTS - 1);
    atomicAdd(&part_s[(size_t)slot * 256 + t], cs[t]);
    atomicAdd(&part_q[(size_t)slot * 256 + t], cq[t]);
  }
}

// gemm2 (round-13 proven): 128x128 out-tile, K=256 in 2 stages, bn1 reduced in prologue.
__global__ void __launch_bounds__(256, 2) k_gemm2(int N, float invn,
    const short* __restrict__ A,
    const short* __restrict__ Bt,
    const float* __restrict__ bias,
    const float* __restrict__ pAs, const float* __restrict__ pAq,
    const float* __restrict__ g1, const float* __restrict__ b1,
    short* __restrict__ C,
    float* __restrict__ part_s, float* __restrict__ part_q)
{
  __shared__ __align__(16) char As[32768];
  __shared__ __align__(16) char Bs[32768];
  __shared__ float scs[256], shs[256];
  __shared__ float cs[128], cq[128];
  int t = threadIdx.x;
  int m0 = blockIdx.x * 128;
  int w = t >> 6, l = t & 63;
  int wr = w >> 1, wc = w & 1;
  int lm = l & 15, kb = l >> 4;

  if (t < 128) { cs[t] = 0.f; cq[t] = 0.f; }
  {
    float s = 0.f, q = 0.f;
    #pragma unroll 4
    for (int i = 0; i < SLOTS; ++i) {
      s += pAs[i * 256 + t];
      q += pAq[i * 256 + t];
    }
    float a, c;
    bn_coef(s, q, invn, g1[t], b1[t], a, c);
    scs[t] = a; shs[t] = c;
  }
  __syncthreads();

  f32x4 acc[4][4];
  #pragma unroll
  for (int j = 0; j < 4; ++j) {
    float bj = bias[wc * 64 + j * 16 + lm];
    #pragma unroll
    for (int i = 0; i < 4; ++i) acc[i][j] = (f32x4){bj, bj, bj, bj};
  }

  #pragma unroll
  for (int s = 0; s < 2; ++s) {
    if (s > 0) __syncthreads();
    #pragma unroll
    for (int r = 0; r < 8; ++r) {
      int p = (r * 256 + t) * 16;
      int row = p >> 8, c = p & 255;
      int gr = m0 + row; if (gr > N - 1) gr = N - 1;
      bf16x8 v = *(const bf16x8*)((const char*)A + (size_t)gr * 512 + s * 256 + c);
      int kg = s * 128 + (c >> 1);
      float4 s0 = *(const float4*)(scs + kg);
      float4 s1 = *(const float4*)(scs + kg + 4);
      float4 h0 = *(const float4*)(shs + kg);
      float4 h1 = *(const float4*)(shs + kg + 4);
      v[0] = f2bf(fmaxf(bf2f((unsigned short)v[0]) * s0.x + h0.x, 0.f));
      v[1] = f2bf(fmaxf(bf2f((unsigned short)v[1]) * s0.y + h0.y, 0.f));
      v[2] = f2bf(fmaxf(bf2f((unsigned short)v[2]) * s0.z + h0.z, 0.f));
      v[3] = f2bf(fmaxf(bf2f((unsigned short)v[3]) * s0.w + h0.w, 0.f));
      v[4] = f2bf(fmaxf(bf2f((unsigned short)v[4]) * s1.x + h1.x, 0.f));
      v[5] = f2bf(fmaxf(bf2f((unsigned short)v[5]) * s1.y + h1.y, 0.f));
      v[6] = f2bf(fmaxf(bf2f((unsigned short)v[6]) * s1.z + h1.z, 0.f));
      v[7] = f2bf(fmaxf(bf2f((unsigned short)v[7]) * s1.w + h1.w, 0.f));
      *(bf16x8*)(As + row * 256 + (c ^ ((row & 7) << 4))) = v;
    }
    #pragma unroll
    for (int r = 0; r < 8; ++r) {
      int p = (r * 256 + t) * 16;
      int col = p >> 8, c = p & 255;
      bf16x8 v = *(const bf16x8*)((const char*)Bt + (size_t)col * 512 + s * 256 + c);
      *(bf16x8*)(Bs + col * 256 + (c ^ ((col & 7) << 4))) = v;
    }
    __syncthreads();
    #pragma unroll
    for (int ks = 0; ks < 4; ++ks) {
      int kB = ks * 64 + kb * 16;
      bf16x8 fa[4], fb[4];
      #pragma unroll
      for (int i = 0; i < 4; ++i) {
        int rl = wr * 64 + i * 16 + lm;
        fa[i] = *(const bf16x8*)(As + rl * 256 + (kB ^ ((rl & 7) << 4)));
      }
      #pragma unroll
      for (int j = 0; j < 4; ++j) {
        int cl = wc * 64 + j * 16 + lm;
        fb[j] = *(const bf16x8*)(Bs + cl * 256 + (kB ^ ((cl & 7) << 4)));
      }
      #pragma unroll
      for (int i = 0; i < 4; ++i)
        #pragma unroll
        for (int j = 0; j < 4; ++j)
          acc[i][j] = __builtin_amdgcn_mfma_f32_16x16x32_bf16(fa[i], fb[j], acc[i][j], 0, 0, 0);
    }
  }

  #pragma unroll
  for (int j = 0; j < 4; ++j) {
    int col = wc * 64 + j * 16 + lm;
    float sv = 0.f, qv = 0.f;
    #pragma unroll
    for (int i = 0; i < 4; ++i) {
      #pragma unroll
      for (int r = 0; r < 4; ++r) {
        int row = m0 + wr * 64 + i * 16 + kb * 4 + r;
        float vv = acc[i][j][r];
        if (row < N) { C[(size_t)row * 128 + col] = f2bf(vv); sv += vv; qv += vv * vv; }
      }
    }
    sv += __shfl_xor(sv, 16); sv += __shfl_xor(sv, 32);
    qv += __shfl_xor(qv, 16); qv += __shfl_xor(qv, 32);
    if (l < 16) { atomicAdd(&cs[col], sv); atomicAdd(&cq[col], qv); }
  }
  __syncthreads();
  if (t < 128) {
    int slot = blockIdx.x & (SLOTS - 1);
    atomicAdd(&part_s[(size_t)slot * 128 + t], cs[t]);
    atomicAdd(&part_q[(size_t)slot * 128 + t], cq[t]);
  }
}

// vn MLP stage 1 (fp32, tiny)
__global__ void k_vn1(const float* __restrict__ vt_pool,
    int vn_mode, const float* __restrict__ vne, const float* __restrict__ t2v,
    const float* __restrict__ vs2, const float* __restrict__ vq2,
    const float* __restrict__ vg2, const float* __restrict__ vb2,
    const float* __restrict__ W1, const float* __restrict__ b1,
    float* __restrict__ t1v, float* __restrict__ s1, float* __restrict__ q1)
{
  __shared__ float vrow[128];
  int g = blockIdx.x, t = threadIdx.x;
  if (t < 128) {
    float vnv;
    if (vn_mode == 0) vnv = vne[t];
    else {
      float sc, sh;
      bn_coef(vs2[t], vq2[t], 1.f / (float)GG, vg2[t], vb2[t], sc, sh);
      vnv = fmaxf(t2v[g * D + t] * sc + sh, 0.f);
    }
    vrow[t] = vt_pool[g * D + t] + vnv;
  }
  __syncthreads();
  float acc = b1[t];
  for (int k = 0; k < 128; ++k) acc += vrow[k] * W1[k * 256 + t];
  t1v[g * 256 + t] = acc;
  atomicAdd(&s1[t], acc);
  atomicAdd(&q1[t], acc * acc);
}

// vn MLP stage 2 (fp32, tiny)
__global__ void k_vn2(const float* __restrict__ t1v,
    const float* __restrict__ s1, const float* __restrict__ q1,
    const float* __restrict__ g1, const float* __restrict__ b1bn,
    const float* __restrict__ W2, const float* __restrict__ b2,
    float* __restrict__ t2v, float* __restrict__ s2, float* __restrict__ q2)
{
  __shared__ float p[256];
  int g = blockIdx.x, t = threadIdx.x;
  for (int u = t; u < 256; u += 128) {
    float sc, sh;
    bn_coef(s1[u], q1[u], 1.f / (float)GG, g1[u], b1bn[u], sc, sh);
    p[u] = fmaxf(t1v[g * 256 + u] * sc + sh, 0.f);
  }
  __syncthreads();
  float acc = b2[t];
  for (int k = 0; k < 256; ++k) acc += p[k] * W2[k * D + t];
  t2v[g * D + t] = acc;
  atomicAdd(&s2[t], acc);
  atomicAdd(&q2[t], acc * acc);
}

// final: out = bn2(z2)
__global__ void k_out(int N, const short* __restrict__ z2,
    const float* __restrict__ s2, const float* __restrict__ q2,
    const float* __restrict__ g2, const float* __restrict__ b2, float* __restrict__ out)
{
  long long idx = (long long)blockIdx.x * 256 + threadIdx.x;
  long long base = idx * 2;
  if (base >= (long long)N * D) return;
  int d = (int)(base & (D - 1));
  float invn = 1.f / (float)N;
  unsigned v = *(const unsigned*)(z2 + base);
  float sc0, sh0, sc1, sh1;
  bn_coef(s2[d], q2[d], invn, g2[d], b2[d], sc0, sh0);
  bn_coef(s2[d + 1], q2[d + 1], invn, g2[d + 1], b2[d + 1], sc1, sh1);
  out[base]     = bf2f((unsigned short)(v & 0xffff)) * sc0 + sh0;
  out[base + 1] = bf2f((unsigned short)(v >> 16))    * sc1 + sh1;
}

extern "C" void kernel_launch(void* const* d_in, const int* in_sizes, int n_in,
                              void* d_out, int out_size, void* d_ws, size_t ws_size,
                              hipStream_t stream) {
  const int*   x     = (const int*)d_in[0];
  const int*   depth = (const int*)d_in[1];
  const int*   eidx  = (const int*)d_in[2];
  const int*   batch = (const int*)d_in[3];
  const float* ea    = (const float*)d_in[4];
  const float* te    = (const float*)d_in[5];
  const float* aemb  = (const float*)d_in[6];
  const float* de    = (const float*)d_in[7];
  const float* vne   = (const float*)d_in[8];
  const float* epsp  = (const float*)d_in[9];
  const float* eW    = (const float*)d_in[10];
  const float* eb    = (const float*)d_in[11];
  const float* gW1   = (const float*)d_in[12];
  const float* gb1   = (const float*)d_in[13];
  const float* gbng  = (const float*)d_in[14];
  const float* gbnb  = (const float*)d_in[15];
  const float* gW2   = (const float*)d_in[16];
  const float* gb2   = (const float*)d_in[17];
  const float* bng   = (const float*)d_in[18];
  const float* bnb   = (const float*)d_in[19];
  const float* vW1   = (const float*)d_in[20];
  const float* vb1   = (const float*)d_in[21];
  const float* vbn1g = (const float*)d_in[22];
  const float* vbn1b = (const float*)d_in[23];
  const float* vW2   = (const float*)d_in[24];
  const float* vb2   = (const float*)d_in[25];
  const float* vbn2g = (const float*)d_in[26];
  const float* vbn2b = (const float*)d_in[27];

  int N = in_sizes[0] / 2;
  int E = in_sizes[2] / 2;
  const int* src = eidx;
  const int* dst = eidx + E;

  char* wsp = (char*)d_ws;
  auto alloc = [&](size_t bytes) -> char* {
    char* p = wsp; wsp += (bytes + 15) & ~(size_t)15; return p;
  };
  short* h2         = (short*)alloc((size_t)(N + 1) * 128 * 2);
  short* am         = (short*)alloc((size_t)N * 128 * 2);
  short* t1         = (short*)alloc((size_t)N * 256 * 2);
  short* z2         = (short*)alloc((size_t)N * 128 * 2);
  short* w1t        = (short*)alloc((size_t)5 * 256 * 128 * 2);
  short* w2t        = (short*)alloc((size_t)5 * 128 * 256 * 2);
  int*   row_ptr    = (int*)alloc((size_t)(N + 1) * 4);
  int*   incl       = (int*)alloc((size_t)N * 4);
  int*   blksum     = (int*)alloc(512 * 4);
  int4*  er         = (int4*)alloc(((size_t)E + 3 * (size_t)N + 16) * 16);
  // zeroed region
  char* zero_base = wsp;
  int*  deg    = (int*)alloc((size_t)N * 4);
  int*  cursor = (int*)alloc((size_t)N * 4);
  float* sp = (float*)wsp;
  float *p1s[5], *p1q[5], *p2s[5], *p2q[5], *s2s[5], *q2s[5];
  for (int l = 0; l < 5; ++l) {
    p1s[l]=sp; sp+=SLOTS*256; p1q[l]=sp; sp+=SLOTS*256;
    p2s[l]=sp; sp+=SLOTS*128; p2q[l]=sp; sp+=SLOTS*128;
    s2s[l]=sp; sp+=128; q2s[l]=sp; sp+=128;
  }
  float *vt[4], *t1v[4], *t2v[4], *vs1[4], *vq1[4], *vs2[4], *vq2[4];
  for (int l = 0; l < 4; ++l) {
    vt[l]=sp;  sp+=GG*D;
    t1v[l]=sp; sp+=GG*256;
    t2v[l]=sp; sp+=GG*D;
    vs1[l]=sp; sp+=256; vq1[l]=sp; sp+=256;
    vs2[l]=sp; sp+=128; vq2[l]=sp; sp+=128;
  }
  size_t zero_bytes = (size_t)((char*)sp - zero_base);
  hipMemsetAsync(zero_base, 0, zero_bytes, stream);

  // CSR build (padded)
  int eblk = (E + 255) / 256;
  int nblk = (N + 255) / 256;
  int B = nblk;
  k_deg<<<eblk, 256, 0, stream>>>(E, dst, deg);
  k_scan1<<<nblk, 256, 0, stream>>>(N, deg, incl, blksum);
  k_scan2<<<1, 512, 0, stream>>>(B, blksum);
  k_scan3<<<nblk, 256, 0, stream>>>(N, incl, blksum, deg, row_ptr);
  k_fill<<<eblk, 256, 0, stream>>>(E, src, dst, ea, row_ptr, cursor, er);
  k_padfill<<<nblk, 256, 0, stream>>>(N, deg, row_ptr, er);
  k_sentinel<<<1, 128, 0, stream>>>(N, h2);

  k_pack<<<(5 * 256 * 128 + 255) / 256, 256, 0, stream>>>(gW1, gW2, w1t, w2t);

  int nblk_a = (N + 31) / 32;
  int nblk_gth = (N + 3) / 4;
  int nblk_m = (N + 127) / 128;
  float invn = 1.f / (float)N;

  for (int l = 0; l < 5; ++l) {
    int mode    = (l == 0) ? 0 : 1;
    int vn_mode = (l == 0) ? 0 : 1;
    int do_pool = (l < 4) ? 1 : 0;
    const float* ps2  = (l > 0) ? s2s[l-1] : s2s[0];
    const float* pq2  = (l > 0) ? q2s[l-1] : q2s[0];
    const float* pg2  = (l > 0) ? bng + (l-1)*D : bng;
    const float* pb2  = (l > 0) ? bnb + (l-1)*D : bnb;
    const float* pt2v = (l > 0) ? t2v[l-1] : t2v[0];
    const float* pvs2 = (l > 0) ? vs2[l-1] : vs2[0];
    const float* pvq2 = (l > 0) ? vq2[l-1] : vq2[0];
    const float* pvg2 = (l > 0) ? vbn2g + (l-1)*D : vbn2g;
    const float* pvb2 = (l > 0) ? vbn2b + (l-1)*D : vbn2b;

    k_nodeprep<<<nblk_a, 256, 0, stream>>>(N, mode, x, depth, te, aemb, de,
        z2, ps2, pq2, pg2, pb2,
        vn_mode, vne, pt2v, pvs2, pvq2, pvg2, pvb2,
        batch, h2, do_pool ? vt[l] : vt[0], do_pool);

    k_gather<<<nblk_gth, 256, 0, stream>>>(N, row_ptr, er,
        eW + l*2*D, eb + l*D, epsp + l, h2, am);

    k_gemm1w<<<nblk_m, 256, 0, stream>>>(N, am, w1t + (size_t)l*256*128,
        gb1 + l*256, t1, p1s[l], p1q[l]);

    k_gemm2<<<nblk_m, 256, 0, stream>>>(N, invn, t1, w2t + (size_t)l*128*256,
        gb2 + l*128, p1s[l], p1q[l], gbng + l*256, gbnb + l*256,
        z2, p2s[l], p2q[l]);

    k_coef<<<1, 128, 0, stream>>>(128, p2s[l], p2q[l], s2s[l], q2s[l]);

    if (l < 4) {
      k_vn1<<<GG, 256, 0, stream>>>(vt[l], vn_mode, vne, pt2v, pvs2, pvq2, pvg2, pvb2,
          vW1 + (size_t)l*128*256, vb1 + l*256, t1v[l], vs1[l], vq1[l]);
      k_vn2<<<GG, 128, 0, stream>>>(t1v[l], vs1[l], vq1[l],
          vbn1g + l*256, vbn1b + l*256,
          vW2 + (size_t)l*256*128, vb2 + l*128, t2v[l], vs2[l], vq2[l]);
    }
  }

  k_out<<<(int)(((long long)N * D / 2 + 255) / 256), 256, 0, stream>>>(N, z2, s2s[4], q2s[4],
      bng + 4*D, bnb + 4*D, (float*)d_out);
}

// Round 16
// 865.267 us; speedup vs baseline: 1.2371x; 1.0404x over previous
//
#include <hip/hip_runtime.h>

#define D 128
#define GG 128
#define SLOTS 64

typedef __attribute__((ext_vector_type(8))) short bf16x8;
typedef __attribute__((ext_vector_type(4))) float f32x4;

__device__ __forceinline__ short f2bf(float f) {
  unsigned u = __float_as_uint(f);
  unsigned r = u + 0x7fffu + ((u >> 16) & 1u);
  return (short)(r >> 16);
}
__device__ __forceinline__ float bf2f(unsigned short h) {
  return __uint_as_float(((unsigned)h) << 16);
}

__device__ __forceinline__ void bn_coef(float s, float q, float invn, float g, float b,
                                        float& sc, float& sh) {
  float mu = s * invn;
  float var = q * invn - mu * mu;
  sc = g * rsqrtf(var + 1e-5f);
  sh = b - mu * sc;
}

// ---------------- CSR build (padded to multiple of 4 per row) ----------------
__global__ void k_deg(int E, const int* __restrict__ dst, int* __restrict__ deg) {
  int e = blockIdx.x * 256 + threadIdx.x;
  if (e < E) atomicAdd(&deg[dst[e]], 1);
}

__global__ void k_scan1(int N, const int* __restrict__ deg,
                        int* __restrict__ incl, int* __restrict__ blksum) {
  __shared__ int s[256];
  int t = threadIdx.x, n = blockIdx.x * 256 + t;
  int v = (n < N) ? ((deg[n] + 3) & ~3) : 0;
  s[t] = v; __syncthreads();
  for (int off = 1; off < 256; off <<= 1) {
    int x = (t >= off) ? s[t - off] : 0;
    __syncthreads();
    s[t] += x;
    __syncthreads();
  }
  if (n < N) incl[n] = s[t];
  if (t == 255) blksum[blockIdx.x] = s[255];
}

__global__ void k_scan2(int B, int* __restrict__ blksum) {
  __shared__ int s[512];
  int t = threadIdx.x;
  s[t] = (t < B) ? blksum[t] : 0;
  __syncthreads();
  for (int off = 1; off < 512; off <<= 1) {
    int x = (t >= off) ? s[t - off] : 0;
    __syncthreads();
    s[t] += x;
    __syncthreads();
  }
  if (t < B) blksum[t] = s[t];
}

__global__ void k_scan3(int N, const int* __restrict__ incl, const int* __restrict__ blksum,
                        const int* __restrict__ deg, int* __restrict__ row_ptr) {
  int n = blockIdx.x * 256 + threadIdx.x;
  if (n >= N) return;
  int b = n >> 8;
  int off = (b > 0) ? blksum[b - 1] : 0;
  int pdeg = (deg[n] + 3) & ~3;
  row_ptr[n] = off + incl[n] - pdeg;
  if (n == N - 1) row_ptr[N] = off + incl[n];
}

__global__ void k_fill(int E, const int* __restrict__ src, const int* __restrict__ dst,
                       const float* __restrict__ ea, const int* __restrict__ row_ptr,
                       int* __restrict__ cursor, int4* __restrict__ er) {
  int e = blockIdx.x * 256 + threadIdx.x;
  if (e >= E) return;
  int d = dst[e];
  int pos = row_ptr[d] + atomicAdd(&cursor[d], 1);
  er[pos] = make_int4(src[e] << 8, __float_as_int(ea[2 * e]), __float_as_int(ea[2 * e + 1]), 0);
}

__global__ void k_padfill(int N, const int* __restrict__ deg, const int* __restrict__ row_ptr,
                          int4* __restrict__ er) {
  int n = blockIdx.x * 256 + threadIdx.x;
  if (n >= N) return;
  int s = row_ptr[n] + deg[n], e = row_ptr[n + 1];
  int4 pad = make_int4(N << 8, 0, 0, 0);
  for (int p = s; p < e; ++p) er[p] = pad;
}

__global__ void k_sentinel(int N, short* __restrict__ h2) {
  h2[(size_t)N * D + threadIdx.x] = f2bf(-1e30f);
}

// pack weights: W1T[l][n=256][k=128], W2T[l][n=128][k=256]  (bf16, n-major)
__global__ void k_pack(const float* __restrict__ gW1, const float* __restrict__ gW2,
                       short* __restrict__ w1t, short* __restrict__ w2t) {
  int id = blockIdx.x * 256 + threadIdx.x;
  if (id < 5 * 256 * 128) {
    int l = id / 32768, r = id % 32768, n = r / 128, k = r % 128;
    w1t[id] = f2bf(gW1[l * 32768 + k * 256 + n]);
  }
  if (id < 5 * 128 * 256) {
    int l = id / 32768, r = id % 32768, n = r / 256, k = r % 256;
    w2t[id] = f2bf(gW2[l * 32768 + k * 128 + n]);
  }
}

// reduce SLOTS partials -> raw sums
__global__ void k_coef(int NC,
                       const float* __restrict__ part_s, const float* __restrict__ part_q,
                       float* __restrict__ outs, float* __restrict__ outq) {
  int t = threadIdx.x;
  if (t >= NC) return;
  float s = 0.f, q = 0.f;
  #pragma unroll 4
  for (int i = 0; i < SLOTS; ++i) {
    s += part_s[i * NC + t];
    q += part_q[i * NC + t];
  }
  outs[t] = s; outq[t] = q;
}

// Fused: h = (encoder | bn2+relu(z2)) + vn[batch]; h2(bf16); pooled per-graph sums.
__global__ void k_nodeprep(int N, int mode,
    const int* __restrict__ x, const int* __restrict__ depth,
    const float* __restrict__ te, const float* __restrict__ ae, const float* __restrict__ de,
    const short* __restrict__ z2, const float* __restrict__ s2, const float* __restrict__ q2,
    const float* __restrict__ g2, const float* __restrict__ b2,
    int vn_mode, const float* __restrict__ vne,
    const float* __restrict__ t2v, const float* __restrict__ vs2, const float* __restrict__ vq2,
    const float* __restrict__ vg2, const float* __restrict__ vb2,
    const int* __restrict__ batch,
    short* __restrict__ h2, float* __restrict__ vt_pool, int do_pool)
{
  int t = threadIdx.x;
  int d0 = (t & 63) * 2;
  int grp = t >> 6;
  int n0 = blockIdx.x * 32 + grp * 8;
  float invn = 1.0f / (float)N;
  float sc0 = 0.f, sh0 = 0.f, sc1 = 0.f, sh1 = 0.f;
  float vsc0 = 0.f, vsh0 = 0.f, vsc1 = 0.f, vsh1 = 0.f;
  if (mode == 1) {
    bn_coef(s2[d0], q2[d0], invn, g2[d0], b2[d0], sc0, sh0);
    bn_coef(s2[d0 + 1], q2[d0 + 1], invn, g2[d0 + 1], b2[d0 + 1], sc1, sh1);
  }
  if (vn_mode == 1) {
    bn_coef(vs2[d0], vq2[d0], 1.0f / (float)GG, vg2[d0], vb2[d0], vsc0, vsh0);
    bn_coef(vs2[d0 + 1], vq2[d0 + 1], 1.0f / (float)GG, vg2[d0 + 1], vb2[d0 + 1], vsc1, vsh1);
  }
  int cur = -1; float a0 = 0.f, a1 = 0.f;
  for (int k = 0; k < 8; ++k) {
    int n = n0 + k;
    if (n >= N) break;
    float h0, h1;
    if (mode == 0) {
      int x0 = x[2 * n], x1 = x[2 * n + 1], dp = depth[n];
      float2 e0 = *(const float2*)(te + (size_t)x0 * D + d0);
      float2 e1 = *(const float2*)(ae + (size_t)x1 * D + d0);
      float2 e2 = *(const float2*)(de + (size_t)dp * D + d0);
      h0 = e0.x + e1.x + e2.x;
      h1 = e0.y + e1.y + e2.y;
    } else {
      unsigned zv = *(const unsigned*)(z2 + (size_t)n * D + d0);
      h0 = fmaxf(bf2f((unsigned short)(zv & 0xffff)) * sc0 + sh0, 0.f);
      h1 = fmaxf(bf2f((unsigned short)(zv >> 16))    * sc1 + sh1, 0.f);
    }
    int g = batch[n];
    float v0, v1;
    if (vn_mode == 0) { v0 = vne[d0]; v1 = vne[d0 + 1]; }
    else {
      float2 tv = *(const float2*)(t2v + (size_t)g * D + d0);
      v0 = fmaxf(tv.x * vsc0 + vsh0, 0.f);
      v1 = fmaxf(tv.y * vsc1 + vsh1, 0.f);
    }
    h0 += v0; h1 += v1;
    unsigned o = ((unsigned)(unsigned short)f2bf(h0)) |
                 (((unsigned)(unsigned short)f2bf(h1)) << 16);
    *(unsigned*)(h2 + (size_t)n * D + d0) = o;
    if (do_pool) {
      if (g != cur) {
        if (cur >= 0) {
          atomicAdd(&vt_pool[cur * D + d0], a0);
          atomicAdd(&vt_pool[cur * D + d0 + 1], a1);
        }
        cur = g; a0 = 0.f; a1 = 0.f;
      }
      a0 += h0; a1 += h1;
    }
  }
  if (do_pool && cur >= 0) {
    atomicAdd(&vt_pool[cur * D + d0], a0);
    atomicAdd(&vt_pool[cur * D + d0 + 1], a1);
  }
}

// Gather aggregation over padded CSR. Wave-uniform CSR range forced into SGPRs so
// er[] loads scalarize (s_load) and edge attrs live in SGPRs; h2 gathers use
// saddr-form loads. Per-slot VALU drops ~2x.
__global__ void __launch_bounds__(256) k_gather(int N,
    const int* __restrict__ row_ptr, const int4* __restrict__ er,
    const float* __restrict__ ew, const float* __restrict__ eb,
    const float* __restrict__ epsp,
    const short* __restrict__ h2, short* __restrict__ am)
{
  int t = threadIdx.x;
  int w = t >> 6, l = t & 63;
  int n = blockIdx.x * 4 + w;
  if (n >= N) return;
  const char* h2b = (const char*)h2;
  int lb = l << 2;
  int d0 = l * 2;
  float ew00 = ew[d0], ew01 = ew[d0 + 1];
  float ew10 = ew[D + d0], ew11 = ew[D + d0 + 1];
  float eb0 = eb[d0], eb1 = eb[d0 + 1];
  float ep1 = 1.0f + epsp[0];
  unsigned hv = *(const unsigned*)(h2b + ((size_t)n << 8) + lb);
  float acc0 = ep1 * bf2f((unsigned short)(hv & 0xffff));
  float acc1 = ep1 * bf2f((unsigned short)(hv >> 16));
  int beg = __builtin_amdgcn_readfirstlane(row_ptr[n]);
  int end = __builtin_amdgcn_readfirstlane(row_ptr[n + 1]);
  for (int i = beg; i < end; i += 4) {
    int4 e0 = er[i], e1 = er[i + 1], e2 = er[i + 2], e3 = er[i + 3];
    int o0 = __builtin_amdgcn_readfirstlane(e0.x);
    int o1 = __builtin_amdgcn_readfirstlane(e1.x);
    int o2 = __builtin_amdgcn_readfirstlane(e2.x);
    int o3 = __builtin_amdgcn_readfirstlane(e3.x);
    unsigned v0 = *(const unsigned*)(h2b + o0 + lb);
    unsigned v1 = *(const unsigned*)(h2b + o1 + lb);
    unsigned v2 = *(const unsigned*)(h2b + o2 + lb);
    unsigned v3 = *(const unsigned*)(h2b + o3 + lb);
    float a0x = __int_as_float(__builtin_amdgcn_readfirstlane(e0.y));
    float a0y = __int_as_float(__builtin_amdgcn_readfirstlane(e0.z));
    float a1x = __int_as_float(__builtin_amdgcn_readfirstlane(e1.y));
    float a1y = __int_as_float(__builtin_amdgcn_readfirstlane(e1.z));
    float a2x = __int_as_float(__builtin_amdgcn_readfirstlane(e2.y));
    float a2y = __int_as_float(__builtin_amdgcn_readfirstlane(e2.z));
    float a3x = __int_as_float(__builtin_amdgcn_readfirstlane(e3.y));
    float a3y = __int_as_float(__builtin_amdgcn_readfirstlane(e3.z));
    acc0 += fmaxf(bf2f((unsigned short)(v0 & 0xffff)) + a0x * ew00 + a0y * ew10 + eb0, 0.f);
    acc1 += fmaxf(bf2f((unsigned short)(v0 >> 16))    + a0x * ew01 + a0y * ew11 + eb1, 0.f);
    acc0 += fmaxf(bf2f((unsigned short)(v1 & 0xffff)) + a1x * ew00 + a1y * ew10 + eb0, 0.f);
    acc1 += fmaxf(bf2f((unsigned short)(v1 >> 16))    + a1x * ew01 + a1y * ew11 + eb1, 0.f);
    acc0 += fmaxf(bf2f((unsigned short)(v2 & 0xffff)) + a2x * ew00 + a2y * ew10 + eb0, 0.f);
    acc1 += fmaxf(bf2f((unsigned short)(v2 >> 16))    + a2x * ew01 + a2y * ew11 + eb1, 0.f);
    acc0 += fmaxf(bf2f((unsigned short)(v3 & 0xffff)) + a3x * ew00 + a3y * ew10 + eb0, 0.f);
    acc1 += fmaxf(bf2f((unsigned short)(v3 >> 16))    + a3x * ew01 + a3y * ew11 + eb1, 0.f);
  }
  unsigned o = ((unsigned)(unsigned short)f2bf(acc0)) |
               (((unsigned)(unsigned short)f2bf(acc1)) << 16);
  *(unsigned*)(am + (size_t)n * D + d0) = o;
}

// gemm1 full-width (r15 proven): t1[128-row tile x 256 cols] = am @ W1 + b1.
__global__ void __launch_bounds__(256, 2) k_gemm1w(int N,
    const short* __restrict__ A, const short* __restrict__ Bt,
    const float* __restrict__ bias,
    short* __restrict__ C,
    float* __restrict__ part_s, float* __restrict__ part_q)
{
  __shared__ __align__(16) char As[32768];
  __shared__ __align__(16) char Bs[32768];
  __shared__ float cs[256], cq[256];
  int t = threadIdx.x;
  int m0 = blockIdx.x * 128;
  int w = t >> 6, l = t & 63;
  int wr = w >> 1, wc = w & 1;
  int lm = l & 15, kb = l >> 4;
  cs[t] = 0.f; cq[t] = 0.f;

  #pragma unroll
  for (int r = 0; r < 8; ++r) {
    int p = (r * 256 + t) * 16;
    int row = p >> 8, c = p & 255;
    int gr = m0 + row; if (gr > N - 1) gr = N - 1;
    bf16x8 v = *(const bf16x8*)((const char*)A + (size_t)gr * 256 + c);
    *(bf16x8*)(As + row * 256 + (c ^ ((row & 7) << 4))) = v;
  }

  #pragma unroll
  for (int ch = 0; ch < 2; ++ch) {
    if (ch > 0) __syncthreads();
    #pragma unroll
    for (int r = 0; r < 8; ++r) {
      int p = (r * 256 + t) * 16;
      int col = p >> 8, c = p & 255;
      bf16x8 v = *(const bf16x8*)((const char*)Bt + (size_t)(ch * 128 + col) * 256 + c);
      *(bf16x8*)(Bs + col * 256 + (c ^ ((col & 7) << 4))) = v;
    }
    __syncthreads();

    f32x4 acc[4][4];
    #pragma unroll
    for (int j = 0; j < 4; ++j) {
      float bj = bias[ch * 128 + wc * 64 + j * 16 + lm];
      #pragma unroll
      for (int i = 0; i < 4; ++i) acc[i][j] = (f32x4){bj, bj, bj, bj};
    }
    #pragma unroll
    for (int ks = 0; ks < 4; ++ks) {
      int kB = ks * 64 + kb * 16;
      bf16x8 fa[4], fb[4];
      #pragma unroll
      for (int i = 0; i < 4; ++i) {
        int rl = wr * 64 + i * 16 + lm;
        fa[i] = *(const bf16x8*)(As + rl * 256 + (kB ^ ((rl & 7) << 4)));
      }
      #pragma unroll
      for (int j = 0; j < 4; ++j) {
        int cl = wc * 64 + j * 16 + lm;
        fb[j] = *(const bf16x8*)(Bs + cl * 256 + (kB ^ ((cl & 7) << 4)));
      }
      #pragma unroll
      for (int i = 0; i < 4; ++i)
        #pragma unroll
        for (int j = 0; j < 4; ++j)
          acc[i][j] = __builtin_amdgcn_mfma_f32_16x16x32_bf16(fa[i], fb[j], acc[i][j], 0, 0, 0);
    }
    #pragma unroll
    for (int j = 0; j < 4; ++j) {
      int col = ch * 128 + wc * 64 + j * 16 + lm;
      float sv = 0.f, qv = 0.f;
      #pragma unroll
      for (int i = 0; i < 4; ++i) {
        #pragma unroll
        for (int r = 0; r < 4; ++r) {
          int row = m0 + wr * 64 + i * 16 + kb * 4 + r;
          float vv = acc[i][j][r];
          if (row < N) { C[(size_t)row * 256 + col] = f2bf(vv); sv += vv; qv += vv * vv; }
        }
      }
      sv += __shfl_xor(sv, 16); sv += __shfl_xor(sv, 32);
      qv += __shfl_xor(qv, 16); qv += __shfl_xor(qv, 32);
      if (l < 16) { atomicAdd(&cs[col], sv); atomicAdd(&cq[col], qv); }
    }
  }
  __syncthreads();
  {
    int slot = blockIdx.x & (SLOTS - 1);
    atomicAdd(&part_s[(size_t)slot * 256 + t], cs[t]);
    atomicAdd(&part_q[(size_t)slot * 256 + t], cq[t]);
  }
}

// gemm2 (r13/r15 proven): 128x128 out-tile, K=256 in 2 stages, bn1 reduced in prologue.
__global__ void __launch_bounds__(256, 2) k_gemm2(int N, float invn,
    const short* __restrict__ A,
    const short* __restrict__ Bt,
    const float* __restrict__ bias,
    const float* __restrict__ pAs, const float* __restrict__ pAq,
    const float* __restrict__ g1, const float* __restrict__ b1,
    short* __restrict__ C,
    float* __restrict__ part_s, float* __restrict__ part_q)
{
  __shared__ __align__(16) char As[32768];
  __shared__ __align__(16) char Bs[32768];
  __shared__ float scs[256], shs[256];
  __shared__ float cs[128], cq[128];
  int t = threadIdx.x;
  int m0 = blockIdx.x * 128;
  int w = t >> 6, l = t & 63;
  int wr = w >> 1, wc = w & 1;
  int lm = l & 15, kb = l >> 4;

  if (t < 128) { cs[t] = 0.f; cq[t] = 0.f; }
  {
    float s = 0.f, q = 0.f;
    #pragma unroll 4
    for (int i = 0; i < SLOTS; ++i) {
      s += pAs[i * 256 + t];
      q += pAq[i * 256 + t];
    }
    float a, c;
    bn_coef(s, q, invn, g1[t], b1[t], a, c);
    scs[t] = a; shs[t] = c;
  }
  __syncthreads();

  f32x4 acc[4][4];
  #pragma unroll
  for (int j = 0; j < 4; ++j) {
    float bj = bias[wc * 64 + j * 16 + lm];
    #pragma unroll
    for (int i = 0; i < 4; ++i) acc[i][j] = (f32x4){bj, bj, bj, bj};
  }

  #pragma unroll
  for (int s = 0; s < 2; ++s) {
    if (s > 0) __syncthreads();
    #pragma unroll
    for (int r = 0; r < 8; ++r) {
      int p = (r * 256 + t) * 16;
      int row = p >> 8, c = p & 255;
      int gr = m0 + row; if (gr > N - 1) gr = N - 1;
      bf16x8 v = *(const bf16x8*)((const char*)A + (size_t)gr * 512 + s * 256 + c);
      int kg = s * 128 + (c >> 1);
      float4 s0 = *(const float4*)(scs + kg);
      float4 s1 = *(const float4*)(scs + kg + 4);
      float4 h0 = *(const float4*)(shs + kg);
      float4 h1 = *(const float4*)(shs + kg + 4);
      v[0] = f2bf(fmaxf(bf2f((unsigned short)v[0]) * s0.x + h0.x, 0.f));
      v[1] = f2bf(fmaxf(bf2f((unsigned short)v[1]) * s0.y + h0.y, 0.f));
      v[2] = f2bf(fmaxf(bf2f((unsigned short)v[2]) * s0.z + h0.z, 0.f));
      v[3] = f2bf(fmaxf(bf2f((unsigned short)v[3]) * s0.w + h0.w, 0.f));
      v[4] = f2bf(fmaxf(bf2f((unsigned short)v[4]) * s1.x + h1.x, 0.f));
      v[5] = f2bf(fmaxf(bf2f((unsigned short)v[5]) * s1.y + h1.y, 0.f));
      v[6] = f2bf(fmaxf(bf2f((unsigned short)v[6]) * s1.z + h1.z, 0.f));
      v[7] = f2bf(fmaxf(bf2f((unsigned short)v[7]) * s1.w + h1.w, 0.f));
      *(bf16x8*)(As + row * 256 + (c ^ ((row & 7) << 4))) = v;
    }
    #pragma unroll
    for (int r = 0; r < 8; ++r) {
      int p = (r * 256 + t) * 16;
      int col = p >> 8, c = p & 255;
      bf16x8 v = *(const bf16x8*)((const char*)Bt + (size_t)col * 512 + s * 256 + c);
      *(bf16x8*)(Bs + col * 256 + (c ^ ((col & 7) << 4))) = v;
    }
    __syncthreads();
    #pragma unroll
    for (int ks = 0; ks < 4; ++ks) {
      int kB = ks * 64 + kb * 16;
      bf16x8 fa[4], fb[4];
      #pragma unroll
      for (int i = 0; i < 4; ++i) {
        int rl = wr * 64 + i * 16 + lm;
        fa[i] = *(const bf16x8*)(As + rl * 256 + (kB ^ ((rl & 7) << 4)));
      }
      #pragma unroll
      for (int j = 0; j < 4; ++j) {
        int cl = wc * 64 + j * 16 + lm;
        fb[j] = *(const bf16x8*)(Bs + cl * 256 + (kB ^ ((cl & 7) << 4)));
      }
      #pragma unroll
      for (int i = 0; i < 4; ++i)
        #pragma unroll
        for (int j = 0; j < 4; ++j)
          acc[i][j] = __builtin_amdgcn_mfma_f32_16x16x32_bf16(fa[i], fb[j], acc[i][j], 0, 0, 0);
    }
  }

  #pragma unroll
  for (int j = 0; j < 4; ++j) {
    int col = wc * 64 + j * 16 + lm;
    float sv = 0.f, qv = 0.f;
    #pragma unroll
    for (int i = 0; i < 4; ++i) {
      #pragma unroll
      for (int r = 0; r < 4; ++r) {
        int row = m0 + wr * 64 + i * 16 + kb * 4 + r;
        float vv = acc[i][j][r];
        if (row < N) { C[(size_t)row * 128 + col] = f2bf(vv); sv += vv; qv += vv * vv; }
      }
    }
    sv += __shfl_xor(sv, 16); sv += __shfl_xor(sv, 32);
    qv += __shfl_xor(qv, 16); qv += __shfl_xor(qv, 32);
    if (l < 16) { atomicAdd(&cs[col], sv); atomicAdd(&cq[col], qv); }
  }
  __syncthreads();
  if (t < 128) {
    int slot = blockIdx.x & (SLOTS - 1);
    atomicAdd(&part_s[(size_t)slot * 128 + t], cs[t]);
    atomicAdd(&part_q[(size_t)slot * 128 + t], cq[t]);
  }
}

// vn MLP stage 1 (fp32, tiny)
__global__ void k_vn1(const float* __restrict__ vt_pool,
    int vn_mode, const float* __restrict__ vne, const float* __restrict__ t2v,
    const float* __restrict__ vs2, const float* __restrict__ vq2,
    const float* __restrict__ vg2, const float* __restrict__ vb2,
    const float* __restrict__ W1, const float* __restrict__ b1,
    float* __restrict__ t1v, float* __restrict__ s1, float* __restrict__ q1)
{
  __shared__ float vrow[128];
  int g = blockIdx.x, t = threadIdx.x;
  if (t < 128) {
    float vnv;
    if (vn_mode == 0) vnv = vne[t];
    else {
      float sc, sh;
      bn_coef(vs2[t], vq2[t], 1.f / (float)GG, vg2[t], vb2[t], sc, sh);
      vnv = fmaxf(t2v[g * D + t] * sc + sh, 0.f);
    }
    vrow[t] = vt_pool[g * D + t] + vnv;
  }
  __syncthreads();
  float acc = b1[t];
  for (int k = 0; k < 128; ++k) acc += vrow[k] * W1[k * 256 + t];
  t1v[g * 256 + t] = acc;
  atomicAdd(&s1[t], acc);
  atomicAdd(&q1[t], acc * acc);
}

// vn MLP stage 2 (fp32, tiny)
__global__ void k_vn2(const float* __restrict__ t1v,
    const float* __restrict__ s1, const float* __restrict__ q1,
    const float* __restrict__ g1, const float* __restrict__ b1bn,
    const float* __restrict__ W2, const float* __restrict__ b2,
    float* __restrict__ t2v, float* __restrict__ s2, float* __restrict__ q2)
{
  __shared__ float p[256];
  int g = blockIdx.x, t = threadIdx.x;
  for (int u = t; u < 256; u += 128) {
    float sc, sh;
    bn_coef(s1[u], q1[u], 1.f / (float)GG, g1[u], b1bn[u], sc, sh);
    p[u] = fmaxf(t1v[g * 256 + u] * sc + sh, 0.f);
  }
  __syncthreads();
  float acc = b2[t];
  for (int k = 0; k < 256; ++k) acc += p[k] * W2[k * D + t];
  t2v[g * D + t] = acc;
  atomicAdd(&s2[t], acc);
  atomicAdd(&q2[t], acc * acc);
}

// final: out = bn2(z2)
__global__ void k_out(int N, const short* __restrict__ z2,
    const float* __restrict__ s2, const float* __restrict__ q2,
    const float* __restrict__ g2, const float* __restrict__ b2, float* __restrict__ out)
{
  long long idx = (long long)blockIdx.x * 256 + threadIdx.x;
  long long base = idx * 2;
  if (base >= (long long)N * D) return;
  int d = (int)(base & (D - 1));
  float invn = 1.f / (float)N;
  unsigned v = *(const unsigned*)(z2 + base);
  float sc0, sh0, sc1, sh1;
  bn_coef(s2[d], q2[d], invn, g2[d], b2[d], sc0, sh0);
  bn_coef(s2[d + 1], q2[d + 1], invn, g2[d + 1], b2[d + 1], sc1, sh1);
  out[base]     = bf2f((unsigned short)(v & 0xffff)) * sc0 + sh0;
  out[base + 1] = bf2f((unsigned short)(v >> 16))    * sc1 + sh1;
}

extern "C" void kernel_launch(void* const* d_in, const int* in_sizes, int n_in,
                              void* d_out, int out_size, void* d_ws, size_t ws_size,
                              hipStream_t stream) {
  const int*   x     = (const int*)d_in[0];
  const int*   depth = (const int*)d_in[1];
  const int*   eidx  = (const int*)d_in[2];
  const int*   batch = (const int*)d_in[3];
  const float* ea    = (const float*)d_in[4];
  const float* te    = (const float*)d_in[5];
  const float* aemb  = (const float*)d_in[6];
  const float* de    = (const float*)d_in[7];
  const float* vne   = (const float*)d_in[8];
  const float* epsp  = (const float*)d_in[9];
  const float* eW    = (const float*)d_in[10];
  const float* eb    = (const float*)d_in[11];
  const float* gW1   = (const float*)d_in[12];
  const float* gb1   = (const float*)d_in[13];
  const float* gbng  = (const float*)d_in[14];
  const float* gbnb  = (const float*)d_in[15];
  const float* gW2   = (const float*)d_in[16];
  const float* gb2   = (const float*)d_in[17];
  const float* bng   = (const float*)d_in[18];
  const float* bnb   = (const float*)d_in[19];
  const float* vW1   = (const float*)d_in[20];
  const float* vb1   = (const float*)d_in[21];
  const float* vbn1g = (const float*)d_in[22];
  const float* vbn1b = (const float*)d_in[23];
  const float* vW2   = (const float*)d_in[24];
  const float* vb2   = (const float*)d_in[25];
  const float* vbn2g = (const float*)d_in[26];
  const float* vbn2b = (const float*)d_in[27];

  int N = in_sizes[0] / 2;
  int E = in_sizes[2] / 2;
  const int* src = eidx;
  const int* dst = eidx + E;

  char* wsp = (char*)d_ws;
  auto alloc = [&](size_t bytes) -> char* {
    char* p = wsp; wsp += (bytes + 15) & ~(size_t)15; return p;
  };
  short* h2         = (short*)alloc((size_t)(N + 1) * 128 * 2);
  short* am         = (short*)alloc((size_t)N * 128 * 2);
  short* t1         = (short*)alloc((size_t)N * 256 * 2);
  short* z2         = (short*)alloc((size_t)N * 128 * 2);
  short* w1t        = (short*)alloc((size_t)5 * 256 * 128 * 2);
  short* w2t        = (short*)alloc((size_t)5 * 128 * 256 * 2);
  int*   row_ptr    = (int*)alloc((size_t)(N + 1) * 4);
  int*   incl       = (int*)alloc((size_t)N * 4);
  int*   blksum     = (int*)alloc(512 * 4);
  int4*  er         = (int4*)alloc(((size_t)E + 3 * (size_t)N + 16) * 16);
  // zeroed region
  char* zero_base = wsp;
  int*  deg    = (int*)alloc((size_t)N * 4);
  int*  cursor = (int*)alloc((size_t)N * 4);
  float* sp = (float*)wsp;
  float *p1s[5], *p1q[5], *p2s[5], *p2q[5], *s2s[5], *q2s[5];
  for (int l = 0; l < 5; ++l) {
    p1s[l]=sp; sp+=SLOTS*256; p1q[l]=sp; sp+=SLOTS*256;
    p2s[l]=sp; sp+=SLOTS*128; p2q[l]=sp; sp+=SLOTS*128;
    s2s[l]=sp; sp+=128; q2s[l]=sp; sp+=128;
  }
  float *vt[4], *t1v[4], *t2v[4], *vs1[4], *vq1[4], *vs2[4], *vq2[4];
  for (int l = 0; l < 4; ++l) {
    vt[l]=sp;  sp+=GG*D;
    t1v[l]=sp; sp+=GG*256;
    t2v[l]=sp; sp+=GG*D;
    vs1[l]=sp; sp+=256; vq1[l]=sp; sp+=256;
    vs2[l]=sp; sp+=128; vq2[l]=sp; sp+=128;
  }
  size_t zero_bytes = (size_t)((char*)sp - zero_base);
  hipMemsetAsync(zero_base, 0, zero_bytes, stream);

  // CSR build (padded)
  int eblk = (E + 255) / 256;
  int nblk = (N + 255) / 256;
  int B = nblk;
  k_deg<<<eblk, 256, 0, stream>>>(E, dst, deg);
  k_scan1<<<nblk, 256, 0, stream>>>(N, deg, incl, blksum);
  k_scan2<<<1, 512, 0, stream>>>(B, blksum);
  k_scan3<<<nblk, 256, 0, stream>>>(N, incl, blksum, deg, row_ptr);
  k_fill<<<eblk, 256, 0, stream>>>(E, src, dst, ea, row_ptr, cursor, er);
  k_padfill<<<nblk, 256, 0, stream>>>(N, deg, row_ptr, er);
  k_sentinel<<<1, 128, 0, stream>>>(N, h2);

  k_pack<<<(5 * 256 * 128 + 255) / 256, 256, 0, stream>>>(gW1, gW2, w1t, w2t);

  int nblk_a = (N + 31) / 32;
  int nblk_gth = (N + 3) / 4;
  int nblk_m = (N + 127) / 128;
  float invn = 1.f / (float)N;

  for (int l = 0; l < 5; ++l) {
    int mode    = (l == 0) ? 0 : 1;
    int vn_mode = (l == 0) ? 0 : 1;
    int do_pool = (l < 4) ? 1 : 0;
    const float* ps2  = (l > 0) ? s2s[l-1] : s2s[0];
    const float* pq2  = (l > 0) ? q2s[l-1] : q2s[0];
    const float* pg2  = (l > 0) ? bng + (l-1)*D : bng;
    const float* pb2  = (l > 0) ? bnb + (l-1)*D : bnb;
    const float* pt2v = (l > 0) ? t2v[l-1] : t2v[0];
    const float* pvs2 = (l > 0) ? vs2[l-1] : vs2[0];
    const float* pvq2 = (l > 0) ? vq2[l-1] : vq2[0];
    const float* pvg2 = (l > 0) ? vbn2g + (l-1)*D : vbn2g;
    const float* pvb2 = (l > 0) ? vbn2b + (l-1)*D : vbn2b;

    k_nodeprep<<<nblk_a, 256, 0, stream>>>(N, mode, x, depth, te, aemb, de,
        z2, ps2, pq2, pg2, pb2,
        vn_mode, vne, pt2v, pvs2, pvq2, pvg2, pvb2,
        batch, h2, do_pool ? vt[l] : vt[0], do_pool);

    k_gather<<<nblk_gth, 256, 0, stream>>>(N, row_ptr, er,
        eW + l*2*D, eb + l*D, epsp + l, h2, am);

    k_gemm1w<<<nblk_m, 256, 0, stream>>>(N, am, w1t + (size_t)l*256*128,
        gb1 + l*256, t1, p1s[l], p1q[l]);

    k_gemm2<<<nblk_m, 256, 0, stream>>>(N, invn, t1, w2t + (size_t)l*128*256,
        gb2 + l*128, p1s[l], p1q[l], gbng + l*256, gbnb + l*256,
        z2, p2s[l], p2q[l]);

    k_coef<<<1, 128, 0, stream>>>(128, p2s[l], p2q[l], s2s[l], q2s[l]);

    if (l < 4) {
      k_vn1<<<GG, 256, 0, stream>>>(vt[l], vn_mode, vne, pt2v, pvs2, pvq2, pvg2, pvb2,
          vW1 + (size_t)l*128*256, vb1 + l*256, t1v[l], vs1[l], vq1[l]);
      k_vn2<<<GG, 128, 0, stream>>>(t1v[l], vs1[l], vq1[l],
          vbn1g + l*256, vbn1b + l*256,
          vW2 + (size_t)l*256*128, vb2 + l*128, t2v[l], vs2[l], vq2[l]);
    }
  }

  k_out<<<(int)(((long long)N * D / 2 + 255) / 256), 256, 0, stream>>>(N, z2, s2s[4], q2s[4],
      bng + 4*D, bnb + 4*D, (float*)d_out);
}

// Round 17
// 837.560 us; speedup vs baseline: 1.2780x; 1.0331x over previous
//
#include <hip/hip_runtime.h>

#define D 128
#define GG 128
#define SLOTS 64

typedef __attribute__((ext_vector_type(8))) short bf16x8;
typedef __attribute__((ext_vector_type(4))) float f32x4;

__device__ __forceinline__ short f2bf(float f) {
  unsigned u = __float_as_uint(f);
  unsigned r = u + 0x7fffu + ((u >> 16) & 1u);
  return (short)(r >> 16);
}
__device__ __forceinline__ float bf2f(unsigned short h) {
  return __uint_as_float(((unsigned)h) << 16);
}

__device__ __forceinline__ void bn_coef(float s, float q, float invn, float g, float b,
                                        float& sc, float& sh) {
  float mu = s * invn;
  float var = q * invn - mu * mu;
  sc = g * rsqrtf(var + 1e-5f);
  sh = b - mu * sc;
}

// ---------------- CSR build (padded to multiple of 4 per row) ----------------
__global__ void k_deg(int E, const int* __restrict__ dst, int* __restrict__ deg) {
  int e = blockIdx.x * 256 + threadIdx.x;
  if (e < E) atomicAdd(&deg[dst[e]], 1);
}

__global__ void k_scan1(int N, const int* __restrict__ deg,
                        int* __restrict__ incl, int* __restrict__ blksum) {
  __shared__ int s[256];
  int t = threadIdx.x, n = blockIdx.x * 256 + t;
  int v = (n < N) ? ((deg[n] + 3) & ~3) : 0;
  s[t] = v; __syncthreads();
  for (int off = 1; off < 256; off <<= 1) {
    int x = (t >= off) ? s[t - off] : 0;
    __syncthreads();
    s[t] += x;
    __syncthreads();
  }
  if (n < N) incl[n] = s[t];
  if (t == 255) blksum[blockIdx.x] = s[255];
}

__global__ void k_scan2(int B, int* __restrict__ blksum) {
  __shared__ int s[512];
  int t = threadIdx.x;
  s[t] = (t < B) ? blksum[t] : 0;
  __syncthreads();
  for (int off = 1; off < 512; off <<= 1) {
    int x = (t >= off) ? s[t - off] : 0;
    __syncthreads();
    s[t] += x;
    __syncthreads();
  }
  if (t < B) blksum[t] = s[t];
}

__global__ void k_scan3(int N, const int* __restrict__ incl, const int* __restrict__ blksum,
                        const int* __restrict__ deg, int* __restrict__ row_ptr) {
  int n = blockIdx.x * 256 + threadIdx.x;
  if (n >= N) return;
  int b = n >> 8;
  int off = (b > 0) ? blksum[b - 1] : 0;
  int pdeg = (deg[n] + 3) & ~3;
  row_ptr[n] = off + incl[n] - pdeg;
  if (n == N - 1) row_ptr[N] = off + incl[n];
}

__global__ void k_fill(int E, const int* __restrict__ src, const int* __restrict__ dst,
                       const float* __restrict__ ea, const int* __restrict__ row_ptr,
                       int* __restrict__ cursor, int4* __restrict__ er) {
  int e = blockIdx.x * 256 + threadIdx.x;
  if (e >= E) return;
  int d = dst[e];
  int pos = row_ptr[d] + atomicAdd(&cursor[d], 1);
  er[pos] = make_int4(src[e] << 8, __float_as_int(ea[2 * e]), __float_as_int(ea[2 * e + 1]), 0);
}

__global__ void k_padfill(int N, const int* __restrict__ deg, const int* __restrict__ row_ptr,
                          int4* __restrict__ er) {
  int n = blockIdx.x * 256 + threadIdx.x;
  if (n >= N) return;
  int s = row_ptr[n] + deg[n], e = row_ptr[n + 1];
  int4 pad = make_int4(N << 8, 0, 0, 0);
  for (int p = s; p < e; ++p) er[p] = pad;
}

__global__ void k_sentinel(int N, short* __restrict__ h2) {
  h2[(size_t)N * D + threadIdx.x] = f2bf(-1e30f);
}

// pack weights: W1T[l][n=256][k=128], W2T[l][n=128][k=256]  (bf16, n-major)
__global__ void k_pack(const float* __restrict__ gW1, const float* __restrict__ gW2,
                       short* __restrict__ w1t, short* __restrict__ w2t) {
  int id = blockIdx.x * 256 + threadIdx.x;
  if (id < 5 * 256 * 128) {
    int l = id / 32768, r = id % 32768, n = r / 128, k = r % 128;
    w1t[id] = f2bf(gW1[l * 32768 + k * 256 + n]);
  }
  if (id < 5 * 128 * 256) {
    int l = id / 32768, r = id % 32768, n = r / 256, k = r % 256;
    w2t[id] = f2bf(gW2[l * 32768 + k * 128 + n]);
  }
}

// reduce SLOTS partials -> raw sums (used only for last layer)
__global__ void k_coef(int NC,
                       const float* __restrict__ part_s, const float* __restrict__ part_q,
                       float* __restrict__ outs, float* __restrict__ outq) {
  int t = threadIdx.x;
  if (t >= NC) return;
  float s = 0.f, q = 0.f;
  #pragma unroll 4
  for (int i = 0; i < SLOTS; ++i) {
    s += part_s[i * NC + t];
    q += part_q[i * NC + t];
  }
  outs[t] = s; outq[t] = q;
}

// Fused: h = (encoder | bn2+relu(z2)) + vn[batch]; h2(bf16); pooled per-graph sums.
__global__ void k_nodeprep(int N, int mode,
    const int* __restrict__ x, const int* __restrict__ depth,
    const float* __restrict__ te, const float* __restrict__ ae, const float* __restrict__ de,
    const short* __restrict__ z2, const float* __restrict__ s2, const float* __restrict__ q2,
    const float* __restrict__ g2, const float* __restrict__ b2,
    int vn_mode, const float* __restrict__ vne,
    const float* __restrict__ t2v, const float* __restrict__ vs2, const float* __restrict__ vq2,
    const float* __restrict__ vg2, const float* __restrict__ vb2,
    const int* __restrict__ batch,
    short* __restrict__ h2, float* __restrict__ vt_pool, int do_pool)
{
  int t = threadIdx.x;
  int d0 = (t & 63) * 2;
  int grp = t >> 6;
  int n0 = blockIdx.x * 32 + grp * 8;
  float invn = 1.0f / (float)N;
  float sc0 = 0.f, sh0 = 0.f, sc1 = 0.f, sh1 = 0.f;
  float vsc0 = 0.f, vsh0 = 0.f, vsc1 = 0.f, vsh1 = 0.f;
  if (mode == 1) {
    bn_coef(s2[d0], q2[d0], invn, g2[d0], b2[d0], sc0, sh0);
    bn_coef(s2[d0 + 1], q2[d0 + 1], invn, g2[d0 + 1], b2[d0 + 1], sc1, sh1);
  }
  if (vn_mode == 1) {
    bn_coef(vs2[d0], vq2[d0], 1.0f / (float)GG, vg2[d0], vb2[d0], vsc0, vsh0);
    bn_coef(vs2[d0 + 1], vq2[d0 + 1], 1.0f / (float)GG, vg2[d0 + 1], vb2[d0 + 1], vsc1, vsh1);
  }
  int cur = -1; float a0 = 0.f, a1 = 0.f;
  for (int k = 0; k < 8; ++k) {
    int n = n0 + k;
    if (n >= N) break;
    float h0, h1;
    if (mode == 0) {
      int x0 = x[2 * n], x1 = x[2 * n + 1], dp = depth[n];
      float2 e0 = *(const float2*)(te + (size_t)x0 * D + d0);
      float2 e1 = *(const float2*)(ae + (size_t)x1 * D + d0);
      float2 e2 = *(const float2*)(de + (size_t)dp * D + d0);
      h0 = e0.x + e1.x + e2.x;
      h1 = e0.y + e1.y + e2.y;
    } else {
      unsigned zv = *(const unsigned*)(z2 + (size_t)n * D + d0);
      h0 = fmaxf(bf2f((unsigned short)(zv & 0xffff)) * sc0 + sh0, 0.f);
      h1 = fmaxf(bf2f((unsigned short)(zv >> 16))    * sc1 + sh1, 0.f);
    }
    int g = batch[n];
    float v0, v1;
    if (vn_mode == 0) { v0 = vne[d0]; v1 = vne[d0 + 1]; }
    else {
      float2 tv = *(const float2*)(t2v + (size_t)g * D + d0);
      v0 = fmaxf(tv.x * vsc0 + vsh0, 0.f);
      v1 = fmaxf(tv.y * vsc1 + vsh1, 0.f);
    }
    h0 += v0; h1 += v1;
    unsigned o = ((unsigned)(unsigned short)f2bf(h0)) |
                 (((unsigned)(unsigned short)f2bf(h1)) << 16);
    *(unsigned*)(h2 + (size_t)n * D + d0) = o;
    if (do_pool) {
      if (g != cur) {
        if (cur >= 0) {
          atomicAdd(&vt_pool[cur * D + d0], a0);
          atomicAdd(&vt_pool[cur * D + d0 + 1], a1);
        }
        cur = g; a0 = 0.f; a1 = 0.f;
      }
      a0 += h0; a1 += h1;
    }
  }
  if (do_pool && cur >= 0) {
    atomicAdd(&vt_pool[cur * D + d0], a0);
    atomicAdd(&vt_pool[cur * D + d0 + 1], a1);
  }
}

// Gather aggregation over padded CSR, wave-uniform CSR scalarized (r16 proven).
__global__ void __launch_bounds__(256) k_gather(int N,
    const int* __restrict__ row_ptr, const int4* __restrict__ er,
    const float* __restrict__ ew, const float* __restrict__ eb,
    const float* __restrict__ epsp,
    const short* __restrict__ h2, short* __restrict__ am)
{
  int t = threadIdx.x;
  int w = t >> 6, l = t & 63;
  int n = blockIdx.x * 4 + w;
  if (n >= N) return;
  const char* h2b = (const char*)h2;
  int lb = l << 2;
  int d0 = l * 2;
  float ew00 = ew[d0], ew01 = ew[d0 + 1];
  float ew10 = ew[D + d0], ew11 = ew[D + d0 + 1];
  float eb0 = eb[d0], eb1 = eb[d0 + 1];
  float ep1 = 1.0f + epsp[0];
  unsigned hv = *(const unsigned*)(h2b + ((size_t)n << 8) + lb);
  float acc0 = ep1 * bf2f((unsigned short)(hv & 0xffff));
  float acc1 = ep1 * bf2f((unsigned short)(hv >> 16));
  int beg = __builtin_amdgcn_readfirstlane(row_ptr[n]);
  int end = __builtin_amdgcn_readfirstlane(row_ptr[n + 1]);
  for (int i = beg; i < end; i += 4) {
    int4 e0 = er[i], e1 = er[i + 1], e2 = er[i + 2], e3 = er[i + 3];
    int o0 = __builtin_amdgcn_readfirstlane(e0.x);
    int o1 = __builtin_amdgcn_readfirstlane(e1.x);
    int o2 = __builtin_amdgcn_readfirstlane(e2.x);
    int o3 = __builtin_amdgcn_readfirstlane(e3.x);
    unsigned v0 = *(const unsigned*)(h2b + o0 + lb);
    unsigned v1 = *(const unsigned*)(h2b + o1 + lb);
    unsigned v2 = *(const unsigned*)(h2b + o2 + lb);
    unsigned v3 = *(const unsigned*)(h2b + o3 + lb);
    float a0x = __int_as_float(__builtin_amdgcn_readfirstlane(e0.y));
    float a0y = __int_as_float(__builtin_amdgcn_readfirstlane(e0.z));
    float a1x = __int_as_float(__builtin_amdgcn_readfirstlane(e1.y));
    float a1y = __int_as_float(__builtin_amdgcn_readfirstlane(e1.z));
    float a2x = __int_as_float(__builtin_amdgcn_readfirstlane(e2.y));
    float a2y = __int_as_float(__builtin_amdgcn_readfirstlane(e2.z));
    float a3x = __int_as_float(__builtin_amdgcn_readfirstlane(e3.y));
    float a3y = __int_as_float(__builtin_amdgcn_readfirstlane(e3.z));
    acc0 += fmaxf(bf2f((unsigned short)(v0 & 0xffff)) + a0x * ew00 + a0y * ew10 + eb0, 0.f);
    acc1 += fmaxf(bf2f((unsigned short)(v0 >> 16))    + a0x * ew01 + a0y * ew11 + eb1, 0.f);
    acc0 += fmaxf(bf2f((unsigned short)(v1 & 0xffff)) + a1x * ew00 + a1y * ew10 + eb0, 0.f);
    acc1 += fmaxf(bf2f((unsigned short)(v1 >> 16))    + a1x * ew01 + a1y * ew11 + eb1, 0.f);
    acc0 += fmaxf(bf2f((unsigned short)(v2 & 0xffff)) + a2x * ew00 + a2y * ew10 + eb0, 0.f);
    acc1 += fmaxf(bf2f((unsigned short)(v2 >> 16))    + a2x * ew01 + a2y * ew11 + eb1, 0.f);
    acc0 += fmaxf(bf2f((unsigned short)(v3 & 0xffff)) + a3x * ew00 + a3y * ew10 + eb0, 0.f);
    acc1 += fmaxf(bf2f((unsigned short)(v3 >> 16))    + a3x * ew01 + a3y * ew11 + eb1, 0.f);
  }
  unsigned o = ((unsigned)(unsigned short)f2bf(acc0)) |
               (((unsigned)(unsigned short)f2bf(acc1)) << 16);
  *(unsigned*)(am + (size_t)n * D + d0) = o;
}

// gemm1 full-width (r15/r16 proven): t1[128-row tile x 256 cols] = am @ W1 + b1.
__global__ void __launch_bounds__(256, 2) k_gemm1w(int N,
    const short* __restrict__ A, const short* __restrict__ Bt,
    const float* __restrict__ bias,
    short* __restrict__ C,
    float* __restrict__ part_s, float* __restrict__ part_q)
{
  __shared__ __align__(16) char As[32768];
  __shared__ __align__(16) char Bs[32768];
  __shared__ float cs[256], cq[256];
  int t = threadIdx.x;
  int m0 = blockIdx.x * 128;
  int w = t >> 6, l = t & 63;
  int wr = w >> 1, wc = w & 1;
  int lm = l & 15, kb = l >> 4;
  cs[t] = 0.f; cq[t] = 0.f;

  #pragma unroll
  for (int r = 0; r < 8; ++r) {
    int p = (r * 256 + t) * 16;
    int row = p >> 8, c = p & 255;
    int gr = m0 + row; if (gr > N - 1) gr = N - 1;
    bf16x8 v = *(const bf16x8*)((const char*)A + (size_t)gr * 256 + c);
    *(bf16x8*)(As + row * 256 + (c ^ ((row & 7) << 4))) = v;
  }

  #pragma unroll
  for (int ch = 0; ch < 2; ++ch) {
    if (ch > 0) __syncthreads();
    #pragma unroll
    for (int r = 0; r < 8; ++r) {
      int p = (r * 256 + t) * 16;
      int col = p >> 8, c = p & 255;
      bf16x8 v = *(const bf16x8*)((const char*)Bt + (size_t)(ch * 128 + col) * 256 + c);
      *(bf16x8*)(Bs + col * 256 + (c ^ ((col & 7) << 4))) = v;
    }
    __syncthreads();

    f32x4 acc[4][4];
    #pragma unroll
    for (int j = 0; j < 4; ++j) {
      float bj = bias[ch * 128 + wc * 64 + j * 16 + lm];
      #pragma unroll
      for (int i = 0; i < 4; ++i) acc[i][j] = (f32x4){bj, bj, bj, bj};
    }
    #pragma unroll
    for (int ks = 0; ks < 4; ++ks) {
      int kB = ks * 64 + kb * 16;
      bf16x8 fa[4], fb[4];
      #pragma unroll
      for (int i = 0; i < 4; ++i) {
        int rl = wr * 64 + i * 16 + lm;
        fa[i] = *(const bf16x8*)(As + rl * 256 + (kB ^ ((rl & 7) << 4)));
      }
      #pragma unroll
      for (int j = 0; j < 4; ++j) {
        int cl = wc * 64 + j * 16 + lm;
        fb[j] = *(const bf16x8*)(Bs + cl * 256 + (kB ^ ((cl & 7) << 4)));
      }
      #pragma unroll
      for (int i = 0; i < 4; ++i)
        #pragma unroll
        for (int j = 0; j < 4; ++j)
          acc[i][j] = __builtin_amdgcn_mfma_f32_16x16x32_bf16(fa[i], fb[j], acc[i][j], 0, 0, 0);
    }
    #pragma unroll
    for (int j = 0; j < 4; ++j) {
      int col = ch * 128 + wc * 64 + j * 16 + lm;
      float sv = 0.f, qv = 0.f;
      #pragma unroll
      for (int i = 0; i < 4; ++i) {
        #pragma unroll
        for (int r = 0; r < 4; ++r) {
          int row = m0 + wr * 64 + i * 16 + kb * 4 + r;
          float vv = acc[i][j][r];
          if (row < N) { C[(size_t)row * 256 + col] = f2bf(vv); sv += vv; qv += vv * vv; }
        }
      }
      sv += __shfl_xor(sv, 16); sv += __shfl_xor(sv, 32);
      qv += __shfl_xor(qv, 16); qv += __shfl_xor(qv, 32);
      if (l < 16) { atomicAdd(&cs[col], sv); atomicAdd(&cq[col], qv); }
    }
  }
  __syncthreads();
  {
    int slot = blockIdx.x & (SLOTS - 1);
    atomicAdd(&part_s[(size_t)slot * 256 + t], cs[t]);
    atomicAdd(&part_q[(size_t)slot * 256 + t], cq[t]);
  }
}

// gemm2 (r13/r15/r16 proven): 128x128 out-tile, K=256 in 2 stages, bn1 reduced in prologue.
__global__ void __launch_bounds__(256, 2) k_gemm2(int N, float invn,
    const short* __restrict__ A,
    const short* __restrict__ Bt,
    const float* __restrict__ bias,
    const float* __restrict__ pAs, const float* __restrict__ pAq,
    const float* __restrict__ g1, const float* __restrict__ b1,
    short* __restrict__ C,
    float* __restrict__ part_s, float* __restrict__ part_q)
{
  __shared__ __align__(16) char As[32768];
  __shared__ __align__(16) char Bs[32768];
  __shared__ float scs[256], shs[256];
  __shared__ float cs[128], cq[128];
  int t = threadIdx.x;
  int m0 = blockIdx.x * 128;
  int w = t >> 6, l = t & 63;
  int wr = w >> 1, wc = w & 1;
  int lm = l & 15, kb = l >> 4;

  if (t < 128) { cs[t] = 0.f; cq[t] = 0.f; }
  {
    float s = 0.f, q = 0.f;
    #pragma unroll 4
    for (int i = 0; i < SLOTS; ++i) {
      s += pAs[i * 256 + t];
      q += pAq[i * 256 + t];
    }
    float a, c;
    bn_coef(s, q, invn, g1[t], b1[t], a, c);
    scs[t] = a; shs[t] = c;
  }
  __syncthreads();

  f32x4 acc[4][4];
  #pragma unroll
  for (int j = 0; j < 4; ++j) {
    float bj = bias[wc * 64 + j * 16 + lm];
    #pragma unroll
    for (int i = 0; i < 4; ++i) acc[i][j] = (f32x4){bj, bj, bj, bj};
  }

  #pragma unroll
  for (int s = 0; s < 2; ++s) {
    if (s > 0) __syncthreads();
    #pragma unroll
    for (int r = 0; r < 8; ++r) {
      int p = (r * 256 + t) * 16;
      int row = p >> 8, c = p & 255;
      int gr = m0 + row; if (gr > N - 1) gr = N - 1;
      bf16x8 v = *(const bf16x8*)((const char*)A + (size_t)gr * 512 + s * 256 + c);
      int kg = s * 128 + (c >> 1);
      float4 s0 = *(const float4*)(scs + kg);
      float4 s1 = *(const float4*)(scs + kg + 4);
      float4 h0 = *(const float4*)(shs + kg);
      float4 h1 = *(const float4*)(shs + kg + 4);
      v[0] = f2bf(fmaxf(bf2f((unsigned short)v[0]) * s0.x + h0.x, 0.f));
      v[1] = f2bf(fmaxf(bf2f((unsigned short)v[1]) * s0.y + h0.y, 0.f));
      v[2] = f2bf(fmaxf(bf2f((unsigned short)v[2]) * s0.z + h0.z, 0.f));
      v[3] = f2bf(fmaxf(bf2f((unsigned short)v[3]) * s0.w + h0.w, 0.f));
      v[4] = f2bf(fmaxf(bf2f((unsigned short)v[4]) * s1.x + h1.x, 0.f));
      v[5] = f2bf(fmaxf(bf2f((unsigned short)v[5]) * s1.y + h1.y, 0.f));
      v[6] = f2bf(fmaxf(bf2f((unsigned short)v[6]) * s1.z + h1.z, 0.f));
      v[7] = f2bf(fmaxf(bf2f((unsigned short)v[7]) * s1.w + h1.w, 0.f));
      *(bf16x8*)(As + row * 256 + (c ^ ((row & 7) << 4))) = v;
    }
    #pragma unroll
    for (int r = 0; r < 8; ++r) {
      int p = (r * 256 + t) * 16;
      int col = p >> 8, c = p & 255;
      bf16x8 v = *(const bf16x8*)((const char*)Bt + (size_t)col * 512 + s * 256 + c);
      *(bf16x8*)(Bs + col * 256 + (c ^ ((col & 7) << 4))) = v;
    }
    __syncthreads();
    #pragma unroll
    for (int ks = 0; ks < 4; ++ks) {
      int kB = ks * 64 + kb * 16;
      bf16x8 fa[4], fb[4];
      #pragma unroll
      for (int i = 0; i < 4; ++i) {
        int rl = wr * 64 + i * 16 + lm;
        fa[i] = *(const bf16x8*)(As + rl * 256 + (kB ^ ((rl & 7) << 4)));
      }
      #pragma unroll
      for (int j = 0; j < 4; ++j) {
        int cl = wc * 64 + j * 16 + lm;
        fb[j] = *(const bf16x8*)(Bs + cl * 256 + (kB ^ ((cl & 7) << 4)));
      }
      #pragma unroll
      for (int i = 0; i < 4; ++i)
        #pragma unroll
        for (int j = 0; j < 4; ++j)
          acc[i][j] = __builtin_amdgcn_mfma_f32_16x16x32_bf16(fa[i], fb[j], acc[i][j], 0, 0, 0);
    }
  }

  #pragma unroll
  for (int j = 0; j < 4; ++j) {
    int col = wc * 64 + j * 16 + lm;
    float sv = 0.f, qv = 0.f;
    #pragma unroll
    for (int i = 0; i < 4; ++i) {
      #pragma unroll
      for (int r = 0; r < 4; ++r) {
        int row = m0 + wr * 64 + i * 16 + kb * 4 + r;
        float vv = acc[i][j][r];
        if (row < N) { C[(size_t)row * 128 + col] = f2bf(vv); sv += vv; qv += vv * vv; }
      }
    }
    sv += __shfl_xor(sv, 16); sv += __shfl_xor(sv, 32);
    qv += __shfl_xor(qv, 16); qv += __shfl_xor(qv, 32);
    if (l < 16) { atomicAdd(&cs[col], sv); atomicAdd(&cq[col], qv); }
  }
  __syncthreads();
  if (t < 128) {
    int slot = blockIdx.x & (SLOTS - 1);
    atomicAdd(&part_s[(size_t)slot * 128 + t], cs[t]);
    atomicAdd(&part_q[(size_t)slot * 128 + t], cq[t]);
  }
}

// vn MLP stage 1 (fp32, tiny). Block 0 additionally reduces the outer-BN partials
// (p2s/p2q -> outs/outq) for the next layer's nodeprep — replaces a k_coef launch.
__global__ void k_vn1(const float* __restrict__ vt_pool,
    int vn_mode, const float* __restrict__ vne, const float* __restrict__ t2v,
    const float* __restrict__ vs2, const float* __restrict__ vq2,
    const float* __restrict__ vg2, const float* __restrict__ vb2,
    const float* __restrict__ W1, const float* __restrict__ b1,
    float* __restrict__ t1v, float* __restrict__ s1, float* __restrict__ q1,
    const float* __restrict__ p2s, const float* __restrict__ p2q,
    float* __restrict__ outs, float* __restrict__ outq)
{
  __shared__ float vrow[128];
  int g = blockIdx.x, t = threadIdx.x;
  if (g == 0 && t >= 128) {
    int c = t - 128;
    float s = 0.f, q = 0.f;
    #pragma unroll 4
    for (int i = 0; i < SLOTS; ++i) {
      s += p2s[i * 128 + c];
      q += p2q[i * 128 + c];
    }
    outs[c] = s; outq[c] = q;
  }
  if (t < 128) {
    float vnv;
    if (vn_mode == 0) vnv = vne[t];
    else {
      float sc, sh;
      bn_coef(vs2[t], vq2[t], 1.f / (float)GG, vg2[t], vb2[t], sc, sh);
      vnv = fmaxf(t2v[g * D + t] * sc + sh, 0.f);
    }
    vrow[t] = vt_pool[g * D + t] + vnv;
  }
  __syncthreads();
  float acc = b1[t];
  for (int k = 0; k < 128; ++k) acc += vrow[k] * W1[k * 256 + t];
  t1v[g * 256 + t] = acc;
  atomicAdd(&s1[t], acc);
  atomicAdd(&q1[t], acc * acc);
}

// vn MLP stage 2 (fp32, tiny)
__global__ void k_vn2(const float* __restrict__ t1v,
    const float* __restrict__ s1, const float* __restrict__ q1,
    const float* __restrict__ g1, const float* __restrict__ b1bn,
    const float* __restrict__ W2, const float* __restrict__ b2,
    float* __restrict__ t2v, float* __restrict__ s2, float* __restrict__ q2)
{
  __shared__ float p[256];
  int g = blockIdx.x, t = threadIdx.x;
  for (int u = t; u < 256; u += 128) {
    float sc, sh;
    bn_coef(s1[u], q1[u], 1.f / (float)GG, g1[u], b1bn[u], sc, sh);
    p[u] = fmaxf(t1v[g * 256 + u] * sc + sh, 0.f);
  }
  __syncthreads();
  float acc = b2[t];
  for (int k = 0; k < 256; ++k) acc += p[k] * W2[k * D + t];
  t2v[g * D + t] = acc;
  atomicAdd(&s2[t], acc);
  atomicAdd(&q2[t], acc * acc);
}

// final: out = bn2(z2), 8 elems/thread (bf16x8 in, 2x float4 out)
__global__ void k_out(int N, const short* __restrict__ z2,
    const float* __restrict__ s2, const float* __restrict__ q2,
    const float* __restrict__ g2, const float* __restrict__ b2, float* __restrict__ out)
{
  long long idx = (long long)blockIdx.x * 256 + threadIdx.x;
  long long base = idx * 8;
  if (base >= (long long)N * D) return;
  int d = (int)(base & (D - 1));
  float invn = 1.f / (float)N;
  bf16x8 v = *(const bf16x8*)(z2 + base);
  float vals[8];
  #pragma unroll
  for (int e = 0; e < 8; ++e) {
    float sc, sh;
    bn_coef(s2[d + e], q2[d + e], invn, g2[d + e], b2[d + e], sc, sh);
    vals[e] = bf2f((unsigned short)v[e]) * sc + sh;
  }
  *(float4*)(out + base)     = make_float4(vals[0], vals[1], vals[2], vals[3]);
  *(float4*)(out + base + 4) = make_float4(vals[4], vals[5], vals[6], vals[7]);
}

extern "C" void kernel_launch(void* const* d_in, const int* in_sizes, int n_in,
                              void* d_out, int out_size, void* d_ws, size_t ws_size,
                              hipStream_t stream) {
  const int*   x     = (const int*)d_in[0];
  const int*   depth = (const int*)d_in[1];
  const int*   eidx  = (const int*)d_in[2];
  const int*   batch = (const int*)d_in[3];
  const float* ea    = (const float*)d_in[4];
  const float* te    = (const float*)d_in[5];
  const float* aemb  = (const float*)d_in[6];
  const float* de    = (const float*)d_in[7];
  const float* vne   = (const float*)d_in[8];
  const float* epsp  = (const float*)d_in[9];
  const float* eW    = (const float*)d_in[10];
  const float* eb    = (const float*)d_in[11];
  const float* gW1   = (const float*)d_in[12];
  const float* gb1   = (const float*)d_in[13];
  const float* gbng  = (const float*)d_in[14];
  const float* gbnb  = (const float*)d_in[15];
  const float* gW2   = (const float*)d_in[16];
  const float* gb2   = (const float*)d_in[17];
  const float* bng   = (const float*)d_in[18];
  const float* bnb   = (const float*)d_in[19];
  const float* vW1   = (const float*)d_in[20];
  const float* vb1   = (const float*)d_in[21];
  const float* vbn1g = (const float*)d_in[22];
  const float* vbn1b = (const float*)d_in[23];
  const float* vW2   = (const float*)d_in[24];
  const float* vb2   = (const float*)d_in[25];
  const float* vbn2g = (const float*)d_in[26];
  const float* vbn2b = (const float*)d_in[27];

  int N = in_sizes[0] / 2;
  int E = in_sizes[2] / 2;
  const int* src = eidx;
  const int* dst = eidx + E;

  char* wsp = (char*)d_ws;
  auto alloc = [&](size_t bytes) -> char* {
    char* p = wsp; wsp += (bytes + 15) & ~(size_t)15; return p;
  };
  short* h2         = (short*)alloc((size_t)(N + 1) * 128 * 2);
  short* am         = (short*)alloc((size_t)N * 128 * 2);
  short* t1         = (short*)alloc((size_t)N * 256 * 2);
  short* z2         = (short*)alloc((size_t)N * 128 * 2);
  short* w1t        = (short*)alloc((size_t)5 * 256 * 128 * 2);
  short* w2t        = (short*)alloc((size_t)5 * 128 * 256 * 2);
  int*   row_ptr    = (int*)alloc((size_t)(N + 1) * 4);
  int*   incl       = (int*)alloc((size_t)N * 4);
  int*   blksum     = (int*)alloc(512 * 4);
  int4*  er         = (int4*)alloc(((size_t)E + 3 * (size_t)N + 16) * 16);
  // zeroed region
  char* zero_base = wsp;
  int*  deg    = (int*)alloc((size_t)N * 4);
  int*  cursor = (int*)alloc((size_t)N * 4);
  float* sp = (float*)wsp;
  float *p1s[5], *p1q[5], *p2s[5], *p2q[5], *s2s[5], *q2s[5];
  for (int l = 0; l < 5; ++l) {
    p1s[l]=sp; sp+=SLOTS*256; p1q[l]=sp; sp+=SLOTS*256;
    p2s[l]=sp; sp+=SLOTS*128; p2q[l]=sp; sp+=SLOTS*128;
    s2s[l]=sp; sp+=128; q2s[l]=sp; sp+=128;
  }
  float *vt[4], *t1v[4], *t2v[4], *vs1[4], *vq1[4], *vs2[4], *vq2[4];
  for (int l = 0; l < 4; ++l) {
    vt[l]=sp;  sp+=GG*D;
    t1v[l]=sp; sp+=GG*256;
    t2v[l]=sp; sp+=GG*D;
    vs1[l]=sp; sp+=256; vq1[l]=sp; sp+=256;
    vs2[l]=sp; sp+=128; vq2[l]=sp; sp+=128;
  }
  size_t zero_bytes = (size_t)((char*)sp - zero_base);
  hipMemsetAsync(zero_base, 0, zero_bytes, stream);

  // CSR build (padded)
  int eblk = (E + 255) / 256;
  int nblk = (N + 255) / 256;
  int B = nblk;
  k_deg<<<eblk, 256, 0, stream>>>(E, dst, deg);
  k_scan1<<<nblk, 256, 0, stream>>>(N, deg, incl, blksum);
  k_scan2<<<1, 512, 0, stream>>>(B, blksum);
  k_scan3<<<nblk, 256, 0, stream>>>(N, incl, blksum, deg, row_ptr);
  k_fill<<<eblk, 256, 0, stream>>>(E, src, dst, ea, row_ptr, cursor, er);
  k_padfill<<<nblk, 256, 0, stream>>>(N, deg, row_ptr, er);
  k_sentinel<<<1, 128, 0, stream>>>(N, h2);

  k_pack<<<(5 * 256 * 128 + 255) / 256, 256, 0, stream>>>(gW1, gW2, w1t, w2t);

  int nblk_a = (N + 31) / 32;
  int nblk_gth = (N + 3) / 4;
  int nblk_m = (N + 127) / 128;
  float invn = 1.f / (float)N;

  for (int l = 0; l < 5; ++l) {
    int mode    = (l == 0) ? 0 : 1;
    int vn_mode = (l == 0) ? 0 : 1;
    int do_pool = (l < 4) ? 1 : 0;
    const float* ps2  = (l > 0) ? s2s[l-1] : s2s[0];
    const float* pq2  = (l > 0) ? q2s[l-1] : q2s[0];
    const float* pg2  = (l > 0) ? bng + (l-1)*D : bng;
    const float* pb2  = (l > 0) ? bnb + (l-1)*D : bnb;
    const float* pt2v = (l > 0) ? t2v[l-1] : t2v[0];
    const float* pvs2 = (l > 0) ? vs2[l-1] : vs2[0];
    const float* pvq2 = (l > 0) ? vq2[l-1] : vq2[0];
    const float* pvg2 = (l > 0) ? vbn2g + (l-1)*D : vbn2g;
    const float* pvb2 = (l > 0) ? vbn2b + (l-1)*D : vbn2b;

    k_nodeprep<<<nblk_a, 256, 0, stream>>>(N, mode, x, depth, te, aemb, de,
        z2, ps2, pq2, pg2, pb2,
        vn_mode, vne, pt2v, pvs2, pvq2, pvg2, pvb2,
        batch, h2, do_pool ? vt[l] : vt[0], do_pool);

    k_gather<<<nblk_gth, 256, 0, stream>>>(N, row_ptr, er,
        eW + l*2*D, eb + l*D, epsp + l, h2, am);

    k_gemm1w<<<nblk_m, 256, 0, stream>>>(N, am, w1t + (size_t)l*256*128,
        gb1 + l*256, t1, p1s[l], p1q[l]);

    k_gemm2<<<nblk_m, 256, 0, stream>>>(N, invn, t1, w2t + (size_t)l*128*256,
        gb2 + l*128, p1s[l], p1q[l], gbng + l*256, gbnb + l*256,
        z2, p2s[l], p2q[l]);

    if (l < 4) {
      // k_vn1 block 0 also reduces p2s/p2q -> s2s/q2s (replaces k_coef launch)
      k_vn1<<<GG, 256, 0, stream>>>(vt[l], vn_mode, vne, pt2v, pvs2, pvq2, pvg2, pvb2,
          vW1 + (size_t)l*128*256, vb1 + l*256, t1v[l], vs1[l], vq1[l],
          p2s[l], p2q[l], s2s[l], q2s[l]);
      k_vn2<<<GG, 128, 0, stream>>>(t1v[l], vs1[l], vq1[l],
          vbn1g + l*256, vbn1b + l*256,
          vW2 + (size_t)l*256*128, vb2 + l*128, t2v[l], vs2[l], vq2[l]);
    } else {
      k_coef<<<1, 128, 0, stream>>>(128, p2s[l], p2q[l], s2s[l], q2s[l]);
    }
  }

  k_out<<<(int)(((long long)N * D / 8 + 255) / 256), 256, 0, stream>>>(N, z2, s2s[4], q2s[4],
      bng + 4*D, bnb + 4*D, (float*)d_out);
}

// Round 18
// 833.052 us; speedup vs baseline: 1.2849x; 1.0054x over previous
//
#include <hip/hip_runtime.h>

#define D 128
#define GG 128
#define SLOTS 64

typedef __attribute__((ext_vector_type(8))) short bf16x8;
typedef __attribute__((ext_vector_type(4))) float f32x4;

__device__ __forceinline__ short f2bf(float f) {
  unsigned u = __float_as_uint(f);
  unsigned r = u + 0x7fffu + ((u >> 16) & 1u);
  return (short)(r >> 16);
}
__device__ __forceinline__ float bf2f(unsigned short h) {
  return __uint_as_float(((unsigned)h) << 16);
}

__device__ __forceinline__ void bn_coef(float s, float q, float invn, float g, float b,
                                        float& sc, float& sh) {
  float mu = s * invn;
  float var = q * invn - mu * mu;
  sc = g * rsqrtf(var + 1e-5f);
  sh = b - mu * sc;
}

// ---------------- CSR build (padded to multiple of 4 per row) ----------------
__global__ void k_deg(int E, const int* __restrict__ dst, int* __restrict__ deg) {
  int e = blockIdx.x * 256 + threadIdx.x;
  if (e < E) atomicAdd(&deg[dst[e]], 1);
}

__global__ void k_scan1(int N, const int* __restrict__ deg,
                        int* __restrict__ incl, int* __restrict__ blksum) {
  __shared__ int s[256];
  int t = threadIdx.x, n = blockIdx.x * 256 + t;
  int v = (n < N) ? ((deg[n] + 3) & ~3) : 0;
  s[t] = v; __syncthreads();
  for (int off = 1; off < 256; off <<= 1) {
    int x = (t >= off) ? s[t - off] : 0;
    __syncthreads();
    s[t] += x;
    __syncthreads();
  }
  if (n < N) incl[n] = s[t];
  if (t == 255) blksum[blockIdx.x] = s[255];
}

__global__ void k_scan2(int B, int* __restrict__ blksum) {
  __shared__ int s[512];
  int t = threadIdx.x;
  s[t] = (t < B) ? blksum[t] : 0;
  __syncthreads();
  for (int off = 1; off < 512; off <<= 1) {
    int x = (t >= off) ? s[t - off] : 0;
    __syncthreads();
    s[t] += x;
    __syncthreads();
  }
  if (t < B) blksum[t] = s[t];
}

__global__ void k_scan3(int N, const int* __restrict__ incl, const int* __restrict__ blksum,
                        const int* __restrict__ deg, int* __restrict__ row_ptr) {
  int n = blockIdx.x * 256 + threadIdx.x;
  if (n >= N) return;
  int b = n >> 8;
  int off = (b > 0) ? blksum[b - 1] : 0;
  int pdeg = (deg[n] + 3) & ~3;
  row_ptr[n] = off + incl[n] - pdeg;
  if (n == N - 1) row_ptr[N] = off + incl[n];
}

__global__ void k_fill(int E, const int* __restrict__ src, const int* __restrict__ dst,
                       const float* __restrict__ ea, const int* __restrict__ row_ptr,
                       int* __restrict__ cursor, int4* __restrict__ er) {
  int e = blockIdx.x * 256 + threadIdx.x;
  if (e >= E) return;
  int d = dst[e];
  int pos = row_ptr[d] + atomicAdd(&cursor[d], 1);
  er[pos] = make_int4(src[e] << 8, __float_as_int(ea[2 * e]), __float_as_int(ea[2 * e + 1]), 0);
}

__global__ void k_padfill(int N, const int* __restrict__ deg, const int* __restrict__ row_ptr,
                          int4* __restrict__ er) {
  int n = blockIdx.x * 256 + threadIdx.x;
  if (n >= N) return;
  int s = row_ptr[n] + deg[n], e = row_ptr[n + 1];
  int4 pad = make_int4(N << 8, 0, 0, 0);
  for (int p = s; p < e; ++p) er[p] = pad;
}

__global__ void k_sentinel(int N, short* __restrict__ h2) {
  h2[(size_t)N * D + threadIdx.x] = f2bf(-1e30f);
}

// pack weights: W1T[l][n=256][k=128], W2T[l][n=128][k=256]  (bf16, n-major)
__global__ void k_pack(const float* __restrict__ gW1, const float* __restrict__ gW2,
                       short* __restrict__ w1t, short* __restrict__ w2t) {
  int id = blockIdx.x * 256 + threadIdx.x;
  if (id < 5 * 256 * 128) {
    int l = id / 32768, r = id % 32768, n = r / 128, k = r % 128;
    w1t[id] = f2bf(gW1[l * 32768 + k * 256 + n]);
  }
  if (id < 5 * 128 * 256) {
    int l = id / 32768, r = id % 32768, n = r / 256, k = r % 256;
    w2t[id] = f2bf(gW2[l * 32768 + k * 128 + n]);
  }
}

// reduce SLOTS partials -> raw sums (used only for last layer)
__global__ void k_coef(int NC,
                       const float* __restrict__ part_s, const float* __restrict__ part_q,
                       float* __restrict__ outs, float* __restrict__ outq) {
  int t = threadIdx.x;
  if (t >= NC) return;
  float s = 0.f, q = 0.f;
  #pragma unroll 4
  for (int i = 0; i < SLOTS; ++i) {
    s += part_s[i * NC + t];
    q += part_q[i * NC + t];
  }
  outs[t] = s; outq[t] = q;
}

// Fused: h = (encoder | bn2+relu(z2)) + vn[batch]; h2(bf16); pooled per-graph sums.
__global__ void k_nodeprep(int N, int mode,
    const int* __restrict__ x, const int* __restrict__ depth,
    const float* __restrict__ te, const float* __restrict__ ae, const float* __restrict__ de,
    const short* __restrict__ z2, const float* __restrict__ s2, const float* __restrict__ q2,
    const float* __restrict__ g2, const float* __restrict__ b2,
    int vn_mode, const float* __restrict__ vne,
    const float* __restrict__ t2v, const float* __restrict__ vs2, const float* __restrict__ vq2,
    const float* __restrict__ vg2, const float* __restrict__ vb2,
    const int* __restrict__ batch,
    short* __restrict__ h2, float* __restrict__ vt_pool, int do_pool)
{
  int t = threadIdx.x;
  int d0 = (t & 63) * 2;
  int grp = t >> 6;
  int n0 = blockIdx.x * 32 + grp * 8;
  float invn = 1.0f / (float)N;
  float sc0 = 0.f, sh0 = 0.f, sc1 = 0.f, sh1 = 0.f;
  float vsc0 = 0.f, vsh0 = 0.f, vsc1 = 0.f, vsh1 = 0.f;
  if (mode == 1) {
    bn_coef(s2[d0], q2[d0], invn, g2[d0], b2[d0], sc0, sh0);
    bn_coef(s2[d0 + 1], q2[d0 + 1], invn, g2[d0 + 1], b2[d0 + 1], sc1, sh1);
  }
  if (vn_mode == 1) {
    bn_coef(vs2[d0], vq2[d0], 1.0f / (float)GG, vg2[d0], vb2[d0], vsc0, vsh0);
    bn_coef(vs2[d0 + 1], vq2[d0 + 1], 1.0f / (float)GG, vg2[d0 + 1], vb2[d0 + 1], vsc1, vsh1);
  }
  int cur = -1; float a0 = 0.f, a1 = 0.f;
  for (int k = 0; k < 8; ++k) {
    int n = n0 + k;
    if (n >= N) break;
    float h0, h1;
    if (mode == 0) {
      int x0 = x[2 * n], x1 = x[2 * n + 1], dp = depth[n];
      float2 e0 = *(const float2*)(te + (size_t)x0 * D + d0);
      float2 e1 = *(const float2*)(ae + (size_t)x1 * D + d0);
      float2 e2 = *(const float2*)(de + (size_t)dp * D + d0);
      h0 = e0.x + e1.x + e2.x;
      h1 = e0.y + e1.y + e2.y;
    } else {
      unsigned zv = *(const unsigned*)(z2 + (size_t)n * D + d0);
      h0 = fmaxf(bf2f((unsigned short)(zv & 0xffff)) * sc0 + sh0, 0.f);
      h1 = fmaxf(bf2f((unsigned short)(zv >> 16))    * sc1 + sh1, 0.f);
    }
    int g = batch[n];
    float v0, v1;
    if (vn_mode == 0) { v0 = vne[d0]; v1 = vne[d0 + 1]; }
    else {
      float2 tv = *(const float2*)(t2v + (size_t)g * D + d0);
      v0 = fmaxf(tv.x * vsc0 + vsh0, 0.f);
      v1 = fmaxf(tv.y * vsc1 + vsh1, 0.f);
    }
    h0 += v0; h1 += v1;
    unsigned o = ((unsigned)(unsigned short)f2bf(h0)) |
                 (((unsigned)(unsigned short)f2bf(h1)) << 16);
    *(unsigned*)(h2 + (size_t)n * D + d0) = o;
    if (do_pool) {
      if (g != cur) {
        if (cur >= 0) {
          atomicAdd(&vt_pool[cur * D + d0], a0);
          atomicAdd(&vt_pool[cur * D + d0 + 1], a1);
        }
        cur = g; a0 = 0.f; a1 = 0.f;
      }
      a0 += h0; a1 += h1;
    }
  }
  if (do_pool && cur >= 0) {
    atomicAdd(&vt_pool[cur * D + d0], a0);
    atomicAdd(&vt_pool[cur * D + d0 + 1], a1);
  }
}

// Gather aggregation over padded CSR, wave-uniform CSR scalarized (r16 proven).
__global__ void __launch_bounds__(256) k_gather(int N,
    const int* __restrict__ row_ptr, const int4* __restrict__ er,
    const float* __restrict__ ew, const float* __restrict__ eb,
    const float* __restrict__ epsp,
    const short* __restrict__ h2, short* __restrict__ am)
{
  int t = threadIdx.x;
  int w = t >> 6, l = t & 63;
  int n = blockIdx.x * 4 + w;
  if (n >= N) return;
  const char* h2b = (const char*)h2;
  int lb = l << 2;
  int d0 = l * 2;
  float ew00 = ew[d0], ew01 = ew[d0 + 1];
  float ew10 = ew[D + d0], ew11 = ew[D + d0 + 1];
  float eb0 = eb[d0], eb1 = eb[d0 + 1];
  float ep1 = 1.0f + epsp[0];
  unsigned hv = *(const unsigned*)(h2b + ((size_t)n << 8) + lb);
  float acc0 = ep1 * bf2f((unsigned short)(hv & 0xffff));
  float acc1 = ep1 * bf2f((unsigned short)(hv >> 16));
  int beg = __builtin_amdgcn_readfirstlane(row_ptr[n]);
  int end = __builtin_amdgcn_readfirstlane(row_ptr[n + 1]);
  for (int i = beg; i < end; i += 4) {
    int4 e0 = er[i], e1 = er[i + 1], e2 = er[i + 2], e3 = er[i + 3];
    int o0 = __builtin_amdgcn_readfirstlane(e0.x);
    int o1 = __builtin_amdgcn_readfirstlane(e1.x);
    int o2 = __builtin_amdgcn_readfirstlane(e2.x);
    int o3 = __builtin_amdgcn_readfirstlane(e3.x);
    unsigned v0 = *(const unsigned*)(h2b + o0 + lb);
    unsigned v1 = *(const unsigned*)(h2b + o1 + lb);
    unsigned v2 = *(const unsigned*)(h2b + o2 + lb);
    unsigned v3 = *(const unsigned*)(h2b + o3 + lb);
    float a0x = __int_as_float(__builtin_amdgcn_readfirstlane(e0.y));
    float a0y = __int_as_float(__builtin_amdgcn_readfirstlane(e0.z));
    float a1x = __int_as_float(__builtin_amdgcn_readfirstlane(e1.y));
    float a1y = __int_as_float(__builtin_amdgcn_readfirstlane(e1.z));
    float a2x = __int_as_float(__builtin_amdgcn_readfirstlane(e2.y));
    float a2y = __int_as_float(__builtin_amdgcn_readfirstlane(e2.z));
    float a3x = __int_as_float(__builtin_amdgcn_readfirstlane(e3.y));
    float a3y = __int_as_float(__builtin_amdgcn_readfirstlane(e3.z));
    acc0 += fmaxf(bf2f((unsigned short)(v0 & 0xffff)) + a0x * ew00 + a0y * ew10 + eb0, 0.f);
    acc1 += fmaxf(bf2f((unsigned short)(v0 >> 16))    + a0x * ew01 + a0y * ew11 + eb1, 0.f);
    acc0 += fmaxf(bf2f((unsigned short)(v1 & 0xffff)) + a1x * ew00 + a1y * ew10 + eb0, 0.f);
    acc1 += fmaxf(bf2f((unsigned short)(v1 >> 16))    + a1x * ew01 + a1y * ew11 + eb1, 0.f);
    acc0 += fmaxf(bf2f((unsigned short)(v2 & 0xffff)) + a2x * ew00 + a2y * ew10 + eb0, 0.f);
    acc1 += fmaxf(bf2f((unsigned short)(v2 >> 16))    + a2x * ew01 + a2y * ew11 + eb1, 0.f);
    acc0 += fmaxf(bf2f((unsigned short)(v3 & 0xffff)) + a3x * ew00 + a3y * ew10 + eb0, 0.f);
    acc1 += fmaxf(bf2f((unsigned short)(v3 >> 16))    + a3x * ew01 + a3y * ew11 + eb1, 0.f);
  }
  unsigned o = ((unsigned)(unsigned short)f2bf(acc0)) |
               (((unsigned)(unsigned short)f2bf(acc1)) << 16);
  *(unsigned*)(am + (size_t)n * D + d0) = o;
}

// gemm1 full-width: t1[128-row tile x 256 cols] = am @ W1 + b1.
// Coalesced C store: per chunk, scatter acc->Bs (dead after MFMA) then contiguous 16B stores.
__global__ void __launch_bounds__(256, 2) k_gemm1w(int N,
    const short* __restrict__ A, const short* __restrict__ Bt,
    const float* __restrict__ bias,
    short* __restrict__ C,
    float* __restrict__ part_s, float* __restrict__ part_q)
{
  __shared__ __align__(16) char As[32768];
  __shared__ __align__(16) char Bs[32768];
  __shared__ float cs[256], cq[256];
  int t = threadIdx.x;
  int m0 = blockIdx.x * 128;
  int w = t >> 6, l = t & 63;
  int wr = w >> 1, wc = w & 1;
  int lm = l & 15, kb = l >> 4;
  cs[t] = 0.f; cq[t] = 0.f;

  #pragma unroll
  for (int r = 0; r < 8; ++r) {
    int p = (r * 256 + t) * 16;
    int row = p >> 8, c = p & 255;
    int gr = m0 + row; if (gr > N - 1) gr = N - 1;
    bf16x8 v = *(const bf16x8*)((const char*)A + (size_t)gr * 256 + c);
    *(bf16x8*)(As + row * 256 + (c ^ ((row & 7) << 4))) = v;
  }

  #pragma unroll
  for (int ch = 0; ch < 2; ++ch) {
    if (ch > 0) __syncthreads();   // Bs free: prev chunk's coalesced reads done
    #pragma unroll
    for (int r = 0; r < 8; ++r) {
      int p = (r * 256 + t) * 16;
      int col = p >> 8, c = p & 255;
      bf16x8 v = *(const bf16x8*)((const char*)Bt + (size_t)(ch * 128 + col) * 256 + c);
      *(bf16x8*)(Bs + col * 256 + (c ^ ((col & 7) << 4))) = v;
    }
    __syncthreads();

    f32x4 acc[4][4];
    #pragma unroll
    for (int j = 0; j < 4; ++j) {
      float bj = bias[ch * 128 + wc * 64 + j * 16 + lm];
      #pragma unroll
      for (int i = 0; i < 4; ++i) acc[i][j] = (f32x4){bj, bj, bj, bj};
    }
    #pragma unroll
    for (int ks = 0; ks < 4; ++ks) {
      int kB = ks * 64 + kb * 16;
      bf16x8 fa[4], fb[4];
      #pragma unroll
      for (int i = 0; i < 4; ++i) {
        int rl = wr * 64 + i * 16 + lm;
        fa[i] = *(const bf16x8*)(As + rl * 256 + (kB ^ ((rl & 7) << 4)));
      }
      #pragma unroll
      for (int j = 0; j < 4; ++j) {
        int cl = wc * 64 + j * 16 + lm;
        fb[j] = *(const bf16x8*)(Bs + cl * 256 + (kB ^ ((cl & 7) << 4)));
      }
      #pragma unroll
      for (int i = 0; i < 4; ++i)
        #pragma unroll
        for (int j = 0; j < 4; ++j)
          acc[i][j] = __builtin_amdgcn_mfma_f32_16x16x32_bf16(fa[i], fb[j], acc[i][j], 0, 0, 0);
    }
    // per-col stats (no global C writes here)
    #pragma unroll
    for (int j = 0; j < 4; ++j) {
      int col = ch * 128 + wc * 64 + j * 16 + lm;
      float sv = 0.f, qv = 0.f;
      #pragma unroll
      for (int i = 0; i < 4; ++i) {
        #pragma unroll
        for (int r = 0; r < 4; ++r) {
          int row = m0 + wr * 64 + i * 16 + kb * 4 + r;
          float vv = acc[i][j][r];
          if (row < N) { sv += vv; qv += vv * vv; }
        }
      }
      sv += __shfl_xor(sv, 16); sv += __shfl_xor(sv, 32);
      qv += __shfl_xor(qv, 16); qv += __shfl_xor(qv, 32);
      if (l < 16) { atomicAdd(&cs[col], sv); atomicAdd(&cq[col], qv); }
    }
    __syncthreads();   // all MFMA reads of Bs done
    // scatter this chunk's C half-tile into Bs (bf16, swizzled)
    #pragma unroll
    for (int j = 0; j < 4; ++j) {
      int colb = (wc * 64 + j * 16 + lm) * 2;
      #pragma unroll
      for (int i = 0; i < 4; ++i) {
        int rowb = wr * 64 + i * 16 + kb * 4;
        #pragma unroll
        for (int r = 0; r < 4; ++r) {
          int row = rowb + r;
          *(short*)(Bs + row * 256 + (colb ^ ((row & 7) << 4))) = f2bf(acc[i][j][r]);
        }
      }
    }
    __syncthreads();
    // coalesced store: 2048 chunks of 16B, wave-contiguous
    #pragma unroll
    for (int it = 0; it < 8; ++it) {
      int c = it * 256 + t;
      int row = c >> 4;
      int rb = (c & 15) * 16;
      int grow = m0 + row;
      bf16x8 v = *(const bf16x8*)(Bs + row * 256 + (rb ^ ((row & 7) << 4)));
      if (grow < N)
        *(bf16x8*)((char*)C + (size_t)grow * 512 + ch * 256 + rb) = v;
    }
  }
  __syncthreads();
  {
    int slot = blockIdx.x & (SLOTS - 1);
    atomicAdd(&part_s[(size_t)slot * 256 + t], cs[t]);
    atomicAdd(&part_q[(size_t)slot * 256 + t], cq[t]);
  }
}

// gemm2: 128x128 out-tile, K=256 in 2 stages, bn1 reduced in prologue.
// Coalesced z2 store via As (dead after compute).
__global__ void __launch_bounds__(256, 2) k_gemm2(int N, float invn,
    const short* __restrict__ A,
    const short* __restrict__ Bt,
    const float* __restrict__ bias,
    const float* __restrict__ pAs, const float* __restrict__ pAq,
    const float* __restrict__ g1, const float* __restrict__ b1,
    short* __restrict__ C,
    float* __restrict__ part_s, float* __restrict__ part_q)
{
  __shared__ __align__(16) char As[32768];
  __shared__ __align__(16) char Bs[32768];
  __shared__ float scs[256], shs[256];
  __shared__ float cs[128], cq[128];
  int t = threadIdx.x;
  int m0 = blockIdx.x * 128;
  int w = t >> 6, l = t & 63;
  int wr = w >> 1, wc = w & 1;
  int lm = l & 15, kb = l >> 4;

  if (t < 128) { cs[t] = 0.f; cq[t] = 0.f; }
  {
    float s = 0.f, q = 0.f;
    #pragma unroll 4
    for (int i = 0; i < SLOTS; ++i) {
      s += pAs[i * 256 + t];
      q += pAq[i * 256 + t];
    }
    float a, c;
    bn_coef(s, q, invn, g1[t], b1[t], a, c);
    scs[t] = a; shs[t] = c;
  }
  __syncthreads();

  f32x4 acc[4][4];
  #pragma unroll
  for (int j = 0; j < 4; ++j) {
    float bj = bias[wc * 64 + j * 16 + lm];
    #pragma unroll
    for (int i = 0; i < 4; ++i) acc[i][j] = (f32x4){bj, bj, bj, bj};
  }

  #pragma unroll
  for (int s = 0; s < 2; ++s) {
    if (s > 0) __syncthreads();
    #pragma unroll
    for (int r = 0; r < 8; ++r) {
      int p = (r * 256 + t) * 16;
      int row = p >> 8, c = p & 255;
      int gr = m0 + row; if (gr > N - 1) gr = N - 1;
      bf16x8 v = *(const bf16x8*)((const char*)A + (size_t)gr * 512 + s * 256 + c);
      int kg = s * 128 + (c >> 1);
      float4 s0 = *(const float4*)(scs + kg);
      float4 s1 = *(const float4*)(scs + kg + 4);
      float4 h0 = *(const float4*)(shs + kg);
      float4 h1 = *(const float4*)(shs + kg + 4);
      v[0] = f2bf(fmaxf(bf2f((unsigned short)v[0]) * s0.x + h0.x, 0.f));
      v[1] = f2bf(fmaxf(bf2f((unsigned short)v[1]) * s0.y + h0.y, 0.f));
      v[2] = f2bf(fmaxf(bf2f((unsigned short)v[2]) * s0.z + h0.z, 0.f));
      v[3] = f2bf(fmaxf(bf2f((unsigned short)v[3]) * s0.w + h0.w, 0.f));
      v[4] = f2bf(fmaxf(bf2f((unsigned short)v[4]) * s1.x + h1.x, 0.f));
      v[5] = f2bf(fmaxf(bf2f((unsigned short)v[5]) * s1.y + h1.y, 0.f));
      v[6] = f2bf(fmaxf(bf2f((unsigned short)v[6]) * s1.z + h1.z, 0.f));
      v[7] = f2bf(fmaxf(bf2f((unsigned short)v[7]) * s1.w + h1.w, 0.f));
      *(bf16x8*)(As + row * 256 + (c ^ ((row & 7) << 4))) = v;
    }
    #pragma unroll
    for (int r = 0; r < 8; ++r) {
      int p = (r * 256 + t) * 16;
      int col = p >> 8, c = p & 255;
      bf16x8 v = *(const bf16x8*)((const char*)Bt + (size_t)col * 512 + s * 256 + c);
      *(bf16x8*)(Bs + col * 256 + (c ^ ((col & 7) << 4))) = v;
    }
    __syncthreads();
    #pragma unroll
    for (int ks = 0; ks < 4; ++ks) {
      int kB = ks * 64 + kb * 16;
      bf16x8 fa[4], fb[4];
      #pragma unroll
      for (int i = 0; i < 4; ++i) {
        int rl = wr * 64 + i * 16 + lm;
        fa[i] = *(const bf16x8*)(As + rl * 256 + (kB ^ ((rl & 7) << 4)));
      }
      #pragma unroll
      for (int j = 0; j < 4; ++j) {
        int cl = wc * 64 + j * 16 + lm;
        fb[j] = *(const bf16x8*)(Bs + cl * 256 + (kB ^ ((cl & 7) << 4)));
      }
      #pragma unroll
      for (int i = 0; i < 4; ++i)
        #pragma unroll
        for (int j = 0; j < 4; ++j)
          acc[i][j] = __builtin_amdgcn_mfma_f32_16x16x32_bf16(fa[i], fb[j], acc[i][j], 0, 0, 0);
    }
  }

  // per-col stats
  #pragma unroll
  for (int j = 0; j < 4; ++j) {
    int col = wc * 64 + j * 16 + lm;
    float sv = 0.f, qv = 0.f;
    #pragma unroll
    for (int i = 0; i < 4; ++i) {
      #pragma unroll
      for (int r = 0; r < 4; ++r) {
        int row = m0 + wr * 64 + i * 16 + kb * 4 + r;
        float vv = acc[i][j][r];
        if (row < N) { sv += vv; qv += vv * vv; }
      }
    }
    sv += __shfl_xor(sv, 16); sv += __shfl_xor(sv, 32);
    qv += __shfl_xor(qv, 16); qv += __shfl_xor(qv, 32);
    if (l < 16) { atomicAdd(&cs[col], sv); atomicAdd(&cq[col], qv); }
  }
  __syncthreads();   // MFMA reads of As done, cs/cq final
  if (t < 128) {
    int slot = blockIdx.x & (SLOTS - 1);
    atomicAdd(&part_s[(size_t)slot * 128 + t], cs[t]);
    atomicAdd(&part_q[(size_t)slot * 128 + t], cq[t]);
  }
  // scatter z2 tile into As (bf16, swizzled)
  #pragma unroll
  for (int j = 0; j < 4; ++j) {
    int colb = (wc * 64 + j * 16 + lm) * 2;
    #pragma unroll
    for (int i = 0; i < 4; ++i) {
      int rowb = wr * 64 + i * 16 + kb * 4;
      #pragma unroll
      for (int r = 0; r < 4; ++r) {
        int row = rowb + r;
        *(short*)(As + row * 256 + (colb ^ ((row & 7) << 4))) = f2bf(acc[i][j][r]);
      }
    }
  }
  __syncthreads();
  // coalesced store: 2048 chunks of 16B
  #pragma unroll
  for (int it = 0; it < 8; ++it) {
    int c = it * 256 + t;
    int row = c >> 4;
    int rb = (c & 15) * 16;
    int grow = m0 + row;
    bf16x8 v = *(const bf16x8*)(As + row * 256 + (rb ^ ((row & 7) << 4)));
    if (grow < N)
      *(bf16x8*)((char*)C + (size_t)grow * 256 + rb) = v;
  }
}

// vn MLP stage 1 (fp32, tiny). Block 0 additionally reduces the outer-BN partials.
__global__ void k_vn1(const float* __restrict__ vt_pool,
    int vn_mode, const float* __restrict__ vne, const float* __restrict__ t2v,
    const float* __restrict__ vs2, const float* __restrict__ vq2,
    const float* __restrict__ vg2, const float* __restrict__ vb2,
    const float* __restrict__ W1, const float* __restrict__ b1,
    float* __restrict__ t1v, float* __restrict__ s1, float* __restrict__ q1,
    const float* __restrict__ p2s, const float* __restrict__ p2q,
    float* __restrict__ outs, float* __restrict__ outq)
{
  __shared__ float vrow[128];
  int g = blockIdx.x, t = threadIdx.x;
  if (g == 0 && t >= 128) {
    int c = t - 128;
    float s = 0.f, q = 0.f;
    #pragma unroll 4
    for (int i = 0; i < SLOTS; ++i) {
      s += p2s[i * 128 + c];
      q += p2q[i * 128 + c];
    }
    outs[c] = s; outq[c] = q;
  }
  if (t < 128) {
    float vnv;
    if (vn_mode == 0) vnv = vne[t];
    else {
      float sc, sh;
      bn_coef(vs2[t], vq2[t], 1.f / (float)GG, vg2[t], vb2[t], sc, sh);
      vnv = fmaxf(t2v[g * D + t] * sc + sh, 0.f);
    }
    vrow[t] = vt_pool[g * D + t] + vnv;
  }
  __syncthreads();
  float acc = b1[t];
  for (int k = 0; k < 128; ++k) acc += vrow[k] * W1[k * 256 + t];
  t1v[g * 256 + t] = acc;
  atomicAdd(&s1[t], acc);
  atomicAdd(&q1[t], acc * acc);
}

// vn MLP stage 2 (fp32, tiny)
__global__ void k_vn2(const float* __restrict__ t1v,
    const float* __restrict__ s1, const float* __restrict__ q1,
    const float* __restrict__ g1, const float* __restrict__ b1bn,
    const float* __restrict__ W2, const float* __restrict__ b2,
    float* __restrict__ t2v, float* __restrict__ s2, float* __restrict__ q2)
{
  __shared__ float p[256];
  int g = blockIdx.x, t = threadIdx.x;
  for (int u = t; u < 256; u += 128) {
    float sc, sh;
    bn_coef(s1[u], q1[u], 1.f / (float)GG, g1[u], b1bn[u], sc, sh);
    p[u] = fmaxf(t1v[g * 256 + u] * sc + sh, 0.f);
  }
  __syncthreads();
  float acc = b2[t];
  for (int k = 0; k < 256; ++k) acc += p[k] * W2[k * D + t];
  t2v[g * D + t] = acc;
  atomicAdd(&s2[t], acc);
  atomicAdd(&q2[t], acc * acc);
}

// final: out = bn2(z2), 8 elems/thread
__global__ void k_out(int N, const short* __restrict__ z2,
    const float* __restrict__ s2, const float* __restrict__ q2,
    const float* __restrict__ g2, const float* __restrict__ b2, float* __restrict__ out)
{
  long long idx = (long long)blockIdx.x * 256 + threadIdx.x;
  long long base = idx * 8;
  if (base >= (long long)N * D) return;
  int d = (int)(base & (D - 1));
  float invn = 1.f / (float)N;
  bf16x8 v = *(const bf16x8*)(z2 + base);
  float vals[8];
  #pragma unroll
  for (int e = 0; e < 8; ++e) {
    float sc, sh;
    bn_coef(s2[d + e], q2[d + e], invn, g2[d + e], b2[d + e], sc, sh);
    vals[e] = bf2f((unsigned short)v[e]) * sc + sh;
  }
  *(float4*)(out + base)     = make_float4(vals[0], vals[1], vals[2], vals[3]);
  *(float4*)(out + base + 4) = make_float4(vals[4], vals[5], vals[6], vals[7]);
}

extern "C" void kernel_launch(void* const* d_in, const int* in_sizes, int n_in,
                              void* d_out, int out_size, void* d_ws, size_t ws_size,
                              hipStream_t stream) {
  const int*   x     = (const int*)d_in[0];
  const int*   depth = (const int*)d_in[1];
  const int*   eidx  = (const int*)d_in[2];
  const int*   batch = (const int*)d_in[3];
  const float* ea    = (const float*)d_in[4];
  const float* te    = (const float*)d_in[5];
  const float* aemb  = (const float*)d_in[6];
  const float* de    = (const float*)d_in[7];
  const float* vne   = (const float*)d_in[8];
  const float* epsp  = (const float*)d_in[9];
  const float* eW    = (const float*)d_in[10];
  const float* eb    = (const float*)d_in[11];
  const float* gW1   = (const float*)d_in[12];
  const float* gb1   = (const float*)d_in[13];
  const float* gbng  = (const float*)d_in[14];
  const float* gbnb  = (const float*)d_in[15];
  const float* gW2   = (const float*)d_in[16];
  const float* gb2   = (const float*)d_in[17];
  const float* bng   = (const float*)d_in[18];
  const float* bnb   = (const float*)d_in[19];
  const float* vW1   = (const float*)d_in[20];
  const float* vb1   = (const float*)d_in[21];
  const float* vbn1g = (const float*)d_in[22];
  const float* vbn1b = (const float*)d_in[23];
  const float* vW2   = (const float*)d_in[24];
  const float* vb2   = (const float*)d_in[25];
  const float* vbn2g = (const float*)d_in[26];
  const float* vbn2b = (const float*)d_in[27];

  int N = in_sizes[0] / 2;
  int E = in_sizes[2] / 2;
  const int* src = eidx;
  const int* dst = eidx + E;

  char* wsp = (char*)d_ws;
  auto alloc = [&](size_t bytes) -> char* {
    char* p = wsp; wsp += (bytes + 15) & ~(size_t)15; return p;
  };
  short* h2         = (short*)alloc((size_t)(N + 1) * 128 * 2);
  short* am         = (short*)alloc((size_t)N * 128 * 2);
  short* t1         = (short*)alloc((size_t)N * 256 * 2);
  short* z2         = (short*)alloc((size_t)N * 128 * 2);
  short* w1t        = (short*)alloc((size_t)5 * 256 * 128 * 2);
  short* w2t        = (short*)alloc((size_t)5 * 128 * 256 * 2);
  int*   row_ptr    = (int*)alloc((size_t)(N + 1) * 4);
  int*   incl       = (int*)alloc((size_t)N * 4);
  int*   blksum     = (int*)alloc(512 * 4);
  int4*  er         = (int4*)alloc(((size_t)E + 3 * (size_t)N + 16) * 16);
  // zeroed region
  char* zero_base = wsp;
  int*  deg    = (int*)alloc((size_t)N * 4);
  int*  cursor = (int*)alloc((size_t)N * 4);
  float* sp = (float*)wsp;
  float *p1s[5], *p1q[5], *p2s[5], *p2q[5], *s2s[5], *q2s[5];
  for (int l = 0; l < 5; ++l) {
    p1s[l]=sp; sp+=SLOTS*256; p1q[l]=sp; sp+=SLOTS*256;
    p2s[l]=sp; sp+=SLOTS*128; p2q[l]=sp; sp+=SLOTS*128;
    s2s[l]=sp; sp+=128; q2s[l]=sp; sp+=128;
  }
  float *vt[4], *t1v[4], *t2v[4], *vs1[4], *vq1[4], *vs2[4], *vq2[4];
  for (int l = 0; l < 4; ++l) {
    vt[l]=sp;  sp+=GG*D;
    t1v[l]=sp; sp+=GG*256;
    t2v[l]=sp; sp+=GG*D;
    vs1[l]=sp; sp+=256; vq1[l]=sp; sp+=256;
    vs2[l]=sp; sp+=128; vq2[l]=sp; sp+=128;
  }
  size_t zero_bytes = (size_t)((char*)sp - zero_base);
  hipMemsetAsync(zero_base, 0, zero_bytes, stream);

  // CSR build (padded)
  int eblk = (E + 255) / 256;
  int nblk = (N + 255) / 256;
  int B = nblk;
  k_deg<<<eblk, 256, 0, stream>>>(E, dst, deg);
  k_scan1<<<nblk, 256, 0, stream>>>(N, deg, incl, blksum);
  k_scan2<<<1, 512, 0, stream>>>(B, blksum);
  k_scan3<<<nblk, 256, 0, stream>>>(N, incl, blksum, deg, row_ptr);
  k_fill<<<eblk, 256, 0, stream>>>(E, src, dst, ea, row_ptr, cursor, er);
  k_padfill<<<nblk, 256, 0, stream>>>(N, deg, row_ptr, er);
  k_sentinel<<<1, 128, 0, stream>>>(N, h2);

  k_pack<<<(5 * 256 * 128 + 255) / 256, 256, 0, stream>>>(gW1, gW2, w1t, w2t);

  int nblk_a = (N + 31) / 32;
  int nblk_gth = (N + 3) / 4;
  int nblk_m = (N + 127) / 128;
  float invn = 1.f / (float)N;

  for (int l = 0; l < 5; ++l) {
    int mode    = (l == 0) ? 0 : 1;
    int vn_mode = (l == 0) ? 0 : 1;
    int do_pool = (l < 4) ? 1 : 0;
    const float* ps2  = (l > 0) ? s2s[l-1] : s2s[0];
    const float* pq2  = (l > 0) ? q2s[l-1] : q2s[0];
    const float* pg2  = (l > 0) ? bng + (l-1)*D : bng;
    const float* pb2  = (l > 0) ? bnb + (l-1)*D : bnb;
    const float* pt2v = (l > 0) ? t2v[l-1] : t2v[0];
    const float* pvs2 = (l > 0) ? vs2[l-1] : vs2[0];
    const float* pvq2 = (l > 0) ? vq2[l-1] : vq2[0];
    const float* pvg2 = (l > 0) ? vbn2g + (l-1)*D : vbn2g;
    const float* pvb2 = (l > 0) ? vbn2b + (l-1)*D : vbn2b;

    k_nodeprep<<<nblk_a, 256, 0, stream>>>(N, mode, x, depth, te, aemb, de,
        z2, ps2, pq2, pg2, pb2,
        vn_mode, vne, pt2v, pvs2, pvq2, pvg2, pvb2,
        batch, h2, do_pool ? vt[l] : vt[0], do_pool);

    k_gather<<<nblk_gth, 256, 0, stream>>>(N, row_ptr, er,
        eW + l*2*D, eb + l*D, epsp + l, h2, am);

    k_gemm1w<<<nblk_m, 256, 0, stream>>>(N, am, w1t + (size_t)l*256*128,
        gb1 + l*256, t1, p1s[l], p1q[l]);

    k_gemm2<<<nblk_m, 256, 0, stream>>>(N, invn, t1, w2t + (size_t)l*128*256,
        gb2 + l*128, p1s[l], p1q[l], gbng + l*256, gbnb + l*256,
        z2, p2s[l], p2q[l]);

    if (l < 4) {
      k_vn1<<<GG, 256, 0, stream>>>(vt[l], vn_mode, vne, pt2v, pvs2, pvq2, pvg2, pvb2,
          vW1 + (size_t)l*128*256, vb1 + l*256, t1v[l], vs1[l], vq1[l],
          p2s[l], p2q[l], s2s[l], q2s[l]);
      k_vn2<<<GG, 128, 0, stream>>>(t1v[l], vs1[l], vq1[l],
          vbn1g + l*256, vbn1b + l*256,
          vW2 + (size_t)l*256*128, vb2 + l*128, t2v[l], vs2[l], vq2[l]);
    } else {
      k_coef<<<1, 128, 0, stream>>>(128, p2s[l], p2q[l], s2s[l], q2s[l]);
    }
  }

  k_out<<<(int)(((long long)N * D / 8 + 255) / 256), 256, 0, stream>>>(N, z2, s2s[4], q2s[4],
      bng + 4*D, bnb + 4*D, (float*)d_out);
}